// Round 14
// baseline (253.133 us; speedup 1.0000x reference)
//
#include <hip/hip_runtime.h>
#include <cstddef>
#include <cstdint>

#define N_BATCH 16
#define C_IN    512
#define L       4096
#define KC      256
#define VC      512
#define NH      8
#define HK      32   // KC/NH
#define HV      64   // VC/NH

using f32x4 = __attribute__((ext_vector_type(4))) float;
using s16x8 = __attribute__((ext_vector_type(8))) short;
using s16x4 = __attribute__((ext_vector_type(4))) short;
using u32x2 = __attribute__((ext_vector_type(2))) unsigned int;

// round-to-nearest-even fp32 -> bf16 bits
static __device__ inline ushort f2bf(float f) {
  uint32_t u = __float_as_uint(f);
  uint32_t r = (u + 0x7FFFu + ((u >> 16) & 1u)) >> 16;
  return (ushort)r;
}
static __device__ inline float bf2f(ushort u) {
  return __uint_as_float((uint32_t)u << 16);
}
static __device__ inline s16x8 mk8(u32x2 lo, u32x2 hi) {
  s16x4 a = __builtin_bit_cast(s16x4, lo);
  s16x4 b = __builtin_bit_cast(s16x4, hi);
  return __builtin_shufflevector(a, b, 0, 1, 2, 3, 4, 5, 6, 7);
}

// ---------------------------------------------------------------------------
// Prep 1: bf16 weight matrix Wb[512][512] (rows 0..255 K, 256..511 Q) + bias
// ---------------------------------------------------------------------------
__global__ __launch_bounds__(256) void k_prep_w(
    const float* __restrict__ Wk, const float* __restrict__ bk,
    const float* __restrict__ Wq, const float* __restrict__ bq,
    ushort* __restrict__ Wb, float* __restrict__ bb)
{
  const int o = blockIdx.x;          // 512
  const float* src; const float* bsrc; int oo;
  if (o < 256) { src = Wk + (size_t)o * C_IN;         bsrc = bk; oo = o; }
  else         { src = Wq + (size_t)(o - 256) * C_IN; bsrc = bq; oo = o - 256; }
  const int t = threadIdx.x;
  Wb[(size_t)o * C_IN + t * 2]     = f2bf(src[t * 2]);
  Wb[(size_t)o * C_IN + t * 2 + 1] = f2bf(src[t * 2 + 1]);
  if (t == 0) bb[o] = bsrc[oo];
}

// ---------------------------------------------------------------------------
// Prep 2: streaming cast x (n,512,4096) f32 -> xb bf16 (same layout).
// ---------------------------------------------------------------------------
__global__ __launch_bounds__(256) void k_prep_xb(const float* __restrict__ x,
                                                 ushort* __restrict__ xb)
{
  size_t i = ((size_t)blockIdx.x * 256 + threadIdx.x) * 8;
  f32x4 a = *(const f32x4*)(x + i);
  f32x4 b = *(const f32x4*)(x + i + 4);
  s16x8 w;
  #pragma unroll
  for (int j = 0; j < 4; ++j) {
    w[j]     = (short)f2bf(a[j]);
    w[j + 4] = (short)f2bf(b[j]);
  }
  *(s16x8*)(xb + i) = w;
}

// ---------------------------------------------------------------------------
// Kernel 1: [K;Q] = Wb @ x + bias, bf16 MFMA, 256x256 tile, BK=64, 8 waves.
// A = Wb via swizzled gload_lds; B = xb subtiled LDS + ds_read_b64_tr_b16.
// oy=0 -> Kbuf; oy=1 -> fused channel softmax -> qT.  (round-13 proven)
// ---------------------------------------------------------------------------
#define QBM 256
#define QBN 256
#define QBK 64

#define TRRD(dst, off_lit)                                                       \
  asm volatile("ds_read_b64_tr_b16 %0, %1 offset:" #off_lit                      \
               : "=v"(dst) : "v"(trp));

__global__ __launch_bounds__(512) void k_kq_mfma(
    const ushort* __restrict__ Wb,   // [512][512] bf16
    const ushort* __restrict__ xb,   // [n][512][4096] bf16
    const float* __restrict__ bb,    // [512]
    ushort* __restrict__ Kbuf,       // [n][256][4096] bf16
    ushort* __restrict__ qT)         // [n][4096][256] bf16 (normalized Q^T)
{
  extern __shared__ __align__(16) char smem[];
  const int n  = blockIdx.z;
  const int oy = blockIdx.y;   // 0 = K rows, 1 = Q rows
  const int lx = blockIdx.x;   // 16 col tiles of 256
  const int tid  = threadIdx.x;
  const int wave = tid >> 6, lane = tid & 63;
  const int wr = wave >> 2, wc = wave & 3;   // 2 x 4

  f32x4 acc[8][4] = {};

  const ushort* gA = Wb + (size_t)(oy * QBM) * C_IN;
  const ushort* gX = xb + (size_t)n * C_IN * L + (size_t)lx * QBN;  // + c*L + l

  #define ASTG(buf, k0)                                                          \
    {                                                                            \
      ushort* As_ = (ushort*)(smem + (buf) * 65536);                             \
      _Pragma("unroll")                                                          \
      for (int i_ = 0; i_ < 4; ++i_) {                                           \
        int rbase_ = wave * 32 + i_ * 8;                                         \
        int row_ = rbase_ + (lane >> 3);                                         \
        int ss_ = (lane & 7) ^ (row_ & 7);                                       \
        __builtin_amdgcn_global_load_lds(                                        \
            (const __attribute__((address_space(1))) uint32_t*)(gA + (size_t)row_ * C_IN + (k0) + ss_ * 8), \
            (__attribute__((address_space(3))) uint32_t*)(As_ + rbase_ * QBK),   \
            16, 0, 0);                                                           \
      }                                                                          \
    }

  #define BSTG(buf, k0)                                                          \
    {                                                                            \
      ushort* Bs_ = (ushort*)(smem + (buf) * 65536 + 32768);                     \
      _Pragma("unroll")                                                          \
      for (int i_ = 0; i_ < 4; ++i_) {                                           \
        int chunk_ = i_ * 512 + tid;                                             \
        int lh_ = chunk_ & 1, crow_ = (chunk_ >> 1) & 3;                         \
        int c4_ = (chunk_ >> 3) & 15, l16_ = chunk_ >> 7;                        \
        __builtin_amdgcn_global_load_lds(                                        \
            (const __attribute__((address_space(1))) uint32_t*)(gX + (size_t)((k0) + c4_ * 4 + crow_) * L + l16_ * 16 + lh_ * 8), \
            (__attribute__((address_space(3))) uint32_t*)(Bs_ + (i_ * 512 + wave * 64) * 8), \
            16, 0, 0);                                                           \
      }                                                                          \
    }

  ASTG(0, 0)
  BSTG(0, 0)
  __syncthreads();

  const int nt = C_IN / QBK;   // 8
  for (int t = 0; t < nt; ++t) {
    if (t < nt - 1) {
      ASTG((t + 1) & 1, (t + 1) * QBK)
      BSTG((t + 1) & 1, (t + 1) * QBK)
    }
    ushort* As = (ushort*)(smem + (t & 1) * 65536);
    ushort* Bs = (ushort*)(smem + (t & 1) * 65536 + 32768);
    __builtin_amdgcn_s_setprio(1);
    #pragma unroll
    for (int ks = 0; ks < 2; ++ks) {
      s16x8 af[8];
      #pragma unroll
      for (int m = 0; m < 8; ++m) {
        int row = wr * 128 + m * 16 + (lane & 15);
        int slot = (ks * 4 + (lane >> 4)) ^ (row & 7);
        af[m] = *(const s16x8*)&As[row * QBK + slot * 8];
      }
      const int trb = wc * 8192 + ks * 1024 + (lane >> 4) * 256 + (lane & 15) * 2;
      __attribute__((address_space(3))) char* trp =
          (__attribute__((address_space(3))) char*)Bs + trb;
      u32x2 lo0, hi0, lo1, hi1, lo2, hi2, lo3, hi3;
      TRRD(lo0, 0)    TRRD(hi0, 128)
      TRRD(lo1, 2048) TRRD(hi1, 2176)
      TRRD(lo2, 4096) TRRD(hi2, 4224)
      TRRD(lo3, 6144) TRRD(hi3, 6272)
      asm volatile("s_waitcnt lgkmcnt(0)" ::: "memory");
      __builtin_amdgcn_sched_barrier(0);
      s16x8 bfr[4];
      bfr[0] = mk8(lo0, hi0);
      bfr[1] = mk8(lo1, hi1);
      bfr[2] = mk8(lo2, hi2);
      bfr[3] = mk8(lo3, hi3);
      #pragma unroll
      for (int m = 0; m < 8; ++m)
        #pragma unroll
        for (int nn = 0; nn < 4; ++nn)
          acc[m][nn] = __builtin_amdgcn_mfma_f32_16x16x32_bf16(af[m], bfr[nn], acc[m][nn], 0, 0, 0);
    }
    __builtin_amdgcn_s_setprio(0);
    __syncthreads();
  }
  #undef ASTG
  #undef BSTG

  if (oy == 0) {
    float* ep = (float*)smem + wave * (16 * 68);
    const int erow = lane >> 4;
    const int ecol = lane & 15;
    const float* bias = bb + wr * 128;
    ushort* outp = Kbuf + ((size_t)n * 256 + wr * 128) * L
                 + (size_t)lx * QBN + wc * 64;
    #pragma unroll
    for (int m = 0; m < 8; ++m) {
      #pragma unroll
      for (int nn = 0; nn < 4; ++nn)
        #pragma unroll
        for (int r = 0; r < 4; ++r)
          ep[(erow * 4 + r) * 68 + nn * 16 + ecol] = acc[m][nn][r];
      #pragma unroll
      for (int p = 0; p < 4; ++p) {
        int row = p * 4 + erow;
        f32x4 v = *(const f32x4*)&ep[row * 68 + ecol * 4];
        float bo = bias[m * 16 + row];
        uint2 pk;
        pk.x = (uint32_t)f2bf(v[0] + bo) | ((uint32_t)f2bf(v[1] + bo) << 16);
        pk.y = (uint32_t)f2bf(v[2] + bo) | ((uint32_t)f2bf(v[3] + bo) << 16);
        *(uint2*)&outp[(size_t)(m * 16 + row) * L + ecol * 4] = pk;
      }
    }
  } else {
    const float* bias = bb + 256 + wr * 128;
    ushort* qbase = qT + (size_t)n * L * KC;
    const int g4 = (lane >> 4) * 4;
    #pragma unroll
    for (int hp = 0; hp < 4; ++hp) {
      const int m0 = 2 * hp, m1 = 2 * hp + 1;
      const float b0_0 = bias[m0 * 16 + g4 + 0], b0_1 = bias[m0 * 16 + g4 + 1];
      const float b0_2 = bias[m0 * 16 + g4 + 2], b0_3 = bias[m0 * 16 + g4 + 3];
      const float b1_0 = bias[m1 * 16 + g4 + 0], b1_1 = bias[m1 * 16 + g4 + 1];
      const float b1_2 = bias[m1 * 16 + g4 + 2], b1_3 = bias[m1 * 16 + g4 + 3];
      #pragma unroll
      for (int nn = 0; nn < 4; ++nn) {
        float v0[4], v1[4];
        v0[0] = acc[m0][nn][0] + b0_0; v0[1] = acc[m0][nn][1] + b0_1;
        v0[2] = acc[m0][nn][2] + b0_2; v0[3] = acc[m0][nn][3] + b0_3;
        v1[0] = acc[m1][nn][0] + b1_0; v1[1] = acc[m1][nn][1] + b1_1;
        v1[2] = acc[m1][nn][2] + b1_2; v1[3] = acc[m1][nn][3] + b1_3;
        float mx = fmaxf(fmaxf(fmaxf(v0[0], v0[1]), fmaxf(v0[2], v0[3])),
                         fmaxf(fmaxf(v1[0], v1[1]), fmaxf(v1[2], v1[3])));
        mx = fmaxf(mx, __shfl_xor(mx, 16));
        mx = fmaxf(mx, __shfl_xor(mx, 32));
        float e0[4], e1[4];
        float s = 0.f;
        #pragma unroll
        for (int r = 0; r < 4; ++r) { e0[r] = __expf(v0[r] - mx); s += e0[r]; }
        #pragma unroll
        for (int r = 0; r < 4; ++r) { e1[r] = __expf(v1[r] - mx); s += e1[r]; }
        s += __shfl_xor(s, 16);
        s += __shfl_xor(s, 32);
        float inv = 1.0f / s;
        int l = lx * QBN + wc * 64 + nn * 16 + (lane & 15);
        ushort* dst = qbase + (size_t)l * KC + wr * 128;
        uint2 p0, p1;
        p0.x = (uint32_t)f2bf(e0[0] * inv) | ((uint32_t)f2bf(e0[1] * inv) << 16);
        p0.y = (uint32_t)f2bf(e0[2] * inv) | ((uint32_t)f2bf(e0[3] * inv) << 16);
        p1.x = (uint32_t)f2bf(e1[0] * inv) | ((uint32_t)f2bf(e1[1] * inv) << 16);
        p1.y = (uint32_t)f2bf(e1[2] * inv) | ((uint32_t)f2bf(e1[3] * inv) << 16);
        *(uint2*)&dst[m0 * 16 + g4] = p0;
        *(uint2*)&dst[m1 * 16 + g4] = p1;
      }
    }
  }
}

// ---------------------------------------------------------------------------
// Reductions
// ---------------------------------------------------------------------------
__device__ inline float blockReduceMax(float v, float* red) {
  #pragma unroll
  for (int off = 32; off > 0; off >>= 1)
    v = fmaxf(v, __shfl_down(v, off, 64));
  int tid = threadIdx.x;
  if ((tid & 63) == 0) red[tid >> 6] = v;
  __syncthreads();
  return fmaxf(fmaxf(red[0], red[1]), fmaxf(red[2], red[3]));
}
__device__ inline float blockReduceSum(float v, float* red) {
  #pragma unroll
  for (int off = 32; off > 0; off >>= 1)
    v += __shfl_down(v, off, 64);
  int tid = threadIdx.x;
  if ((tid & 63) == 0) red[tid >> 6] = v;
  __syncthreads();
  return red[0] + red[1] + red[2] + red[3];
}

// ---------------------------------------------------------------------------
// Kernel 2: K softmax stats over L per (n,row) -> kmax, kinv (stats only)
// ---------------------------------------------------------------------------
__global__ __launch_bounds__(256) void k_kstats3(const ushort* __restrict__ Kbuf,
                                                 float* __restrict__ kmax,
                                                 float* __restrict__ kinv)
{
  const int r = blockIdx.x;
  const int n = blockIdx.y;
  const ushort* row = Kbuf + ((size_t)n * 256 + r) * L;
  __shared__ float red1[4];
  __shared__ float red2[4];
  const int tid = threadIdx.x;
  s16x8 a = *(const s16x8*)(row + tid * 16);
  s16x8 b = *(const s16x8*)(row + tid * 16 + 8);
  float v[16];
  #pragma unroll
  for (int j = 0; j < 8; ++j) { v[j] = bf2f((ushort)a[j]); v[8 + j] = bf2f((ushort)b[j]); }
  float m = -3.0e38f;
  #pragma unroll
  for (int j = 0; j < 16; ++j) m = fmaxf(m, v[j]);
  m = blockReduceMax(m, red1);
  float s = 0.f;
  #pragma unroll
  for (int j = 0; j < 16; ++j) s += __expf(v[j] - m);
  s = blockReduceSum(s, red2);
  if (tid == 0) { kmax[n * KC + r] = m; kinv[n * KC + r] = 1.0f / s; }
}

// ---------------------------------------------------------------------------
// Kernel 3: G[c][k] = sum_l x[c,l] * softmax(K)[k,l]  (per n, l-chunk part).
// ---------------------------------------------------------------------------
#define GBK 64

__global__ __launch_bounds__(512) void k_G(
    const ushort* __restrict__ xb,   // [n][512][4096] bf16
    const ushort* __restrict__ Kbuf, // [n][256][4096] bf16
    const float* __restrict__ kmax,
    const float* __restrict__ kinv,
    float* __restrict__ Gp)          // [n][4][512][256] f32
{
  extern __shared__ __align__(16) char smem[];
  const int cm = blockIdx.x;   // 4 c-tiles of 128
  const int lc = blockIdx.y;   // 4 l-chunks of 1024
  const int n  = blockIdx.z;
  const int tid  = threadIdx.x;
  const int wave = tid >> 6, lane = tid & 63;
  const int wr = wave >> 2, wc = wave & 3;   // 2 x 4

  f32x4 acc[4][4] = {};

  const ushort* gxb = xb   + ((size_t)n * C_IN + cm * 128) * L + lc * 1024;
  const ushort* gK  = Kbuf + (size_t)n * 256 * L + lc * 1024;

  const int brow = tid >> 1;
  const int bseg0 = (tid & 1) * 4;
  const float mk = kmax[n * KC + brow];
  const float ik = kinv[n * KC + brow];

  #define ASTAGE(buf, k0)                                                        \
    {                                                                            \
      ushort* As_ = (ushort*)(smem + (buf) * 49152);                             \
      _Pragma("unroll")                                                          \
      for (int i_ = 0; i_ < 2; ++i_) {                                           \
        int rbase_ = wave * 16 + i_ * 8;                                         \
        int row_ = rbase_ + (lane >> 3);                                         \
        int ss_ = (lane & 7) ^ (row_ & 7);                                       \
        __builtin_amdgcn_global_load_lds(                                        \
            (const __attribute__((address_space(1))) uint32_t*)(gxb + (size_t)row_ * L + (k0) + ss_ * 8), \
            (__attribute__((address_space(3))) uint32_t*)(As_ + rbase_ * GBK),   \
            16, 0, 0);                                                           \
      }                                                                          \
    }

  #define BLOAD(k0)                                                              \
    _Pragma("unroll")                                                            \
    for (int i_ = 0; i_ < 4; ++i_)                                               \
      bk[i_] = *(const s16x8*)(gK + (size_t)brow * L + (k0) + (bseg0 + i_) * 8);

  #define BWRITE(buf)                                                            \
    {                                                                            \
      ushort* Bs_ = (ushort*)(smem + (buf) * 49152 + 16384);                     \
      _Pragma("unroll")                                                          \
      for (int i_ = 0; i_ < 4; ++i_) {                                           \
        s16x8 w_;                                                                \
        _Pragma("unroll")                                                        \
        for (int j_ = 0; j_ < 8; ++j_)                                           \
          w_[j_] = (short)f2bf(__expf(bf2f((ushort)bk[i_][j_]) - mk) * ik);      \
        *(s16x8*)&Bs_[brow * GBK + ((bseg0 + i_) ^ (brow & 7)) * 8] = w_;        \
      }                                                                          \
    }

  s16x8 bk[4];

  BLOAD(0)
  ASTAGE(0, 0)
  BWRITE(0)
  __syncthreads();

  const int nt = 1024 / GBK;   // 16
  for (int t = 0; t < nt; ++t) {
    const int cb = t & 1, nb = cb ^ 1;
    if (t < nt - 1) {
      BLOAD((t + 1) * GBK)
      ASTAGE(nb, (t + 1) * GBK)
    }
    ushort* As = (ushort*)(smem + cb * 49152);
    ushort* Bs = (ushort*)(smem + cb * 49152 + 16384);
    __builtin_amdgcn_s_setprio(1);
    #pragma unroll
    for (int ks = 0; ks < 2; ++ks) {
      s16x8 af[4], bfr[4];
      #pragma unroll
      for (int m = 0; m < 4; ++m) {
        int row = wr * 64 + m * 16 + (lane & 15);
        int slot = (ks * 4 + (lane >> 4)) ^ (row & 7);
        af[m] = *(const s16x8*)&As[row * GBK + slot * 8];
      }
      #pragma unroll
      for (int nn = 0; nn < 4; ++nn) {
        int row = wc * 64 + nn * 16 + (lane & 15);
        int slot = (ks * 4 + (lane >> 4)) ^ (row & 7);
        bfr[nn] = *(const s16x8*)&Bs[row * GBK + slot * 8];
      }
      #pragma unroll
      for (int m = 0; m < 4; ++m)
        #pragma unroll
        for (int nn = 0; nn < 4; ++nn)
          acc[m][nn] = __builtin_amdgcn_mfma_f32_16x16x32_bf16(af[m], bfr[nn], acc[m][nn], 0, 0, 0);
    }
    __builtin_amdgcn_s_setprio(0);
    if (t < nt - 1) BWRITE(nb)
    __syncthreads();
  }
  #undef ASTAGE
  #undef BLOAD
  #undef BWRITE

  float* ep = (float*)smem + wave * (16 * 68);
  const int erow = lane >> 4;
  const int ecol = lane & 15;
  float* op = Gp + (((size_t)n * 4 + lc) * 512 + cm * 128 + wr * 64) * 256 + wc * 64;
  #pragma unroll
  for (int m = 0; m < 4; ++m) {
    #pragma unroll
    for (int nn = 0; nn < 4; ++nn)
      #pragma unroll
      for (int r = 0; r < 4; ++r)
        ep[(erow * 4 + r) * 68 + nn * 16 + ecol] = acc[m][nn][r];
    #pragma unroll
    for (int p = 0; p < 4; ++p) {
      int row16 = p * 4 + erow;
      f32x4 v = *(const f32x4*)&ep[row16 * 68 + ecol * 4];
      *(f32x4*)&op[(size_t)(m * 16 + row16) * 256 + ecol * 4] = v;
    }
  }
}

// ---------------------------------------------------------------------------
// Kernel 4a: F[h][o][c] = sum_v We[o][h*64+v] * Wv[h*64+v][c]  (bf16)
//            Fb[h][o]   = sum_v We[o][h*64+v] * bv[h*64+v]     (f32)
// ---------------------------------------------------------------------------
__global__ __launch_bounds__(256) void k_F(
    const float* __restrict__ Wv, const float* __restrict__ bv,
    const float* __restrict__ We,
    ushort* __restrict__ F, float* __restrict__ Fb)
{
  const int h  = blockIdx.x;   // 8
  const int og = blockIdx.y;   // 32
  const int tid = threadIdx.x;
  __shared__ float Ws[16][64];
  #pragma unroll
  for (int i = 0; i < 4; ++i) {
    int e = tid + i * 256;
    int o = e >> 6, v = e & 63;
    Ws[o][v] = We[(size_t)(og * 16 + o) * VC + h * 64 + v];
  }
  __syncthreads();
  const int c2 = tid * 2;
  float acc[16][2] = {};
  for (int v = 0; v < 64; ++v) {
    float2 w = *(const float2*)&Wv[(size_t)(h * 64 + v) * C_IN + c2];
    #pragma unroll
    for (int o = 0; o < 16; ++o) {
      acc[o][0] += Ws[o][v] * w.x;
      acc[o][1] += Ws[o][v] * w.y;
    }
  }
  ushort* Fh = F + ((size_t)h * 512 + og * 16) * C_IN;
  #pragma unroll
  for (int o = 0; o < 16; ++o) {
    uint32_t pk = (uint32_t)f2bf(acc[o][0]) | ((uint32_t)f2bf(acc[o][1]) << 16);
    *(uint32_t*)&Fh[(size_t)o * C_IN + c2] = pk;
  }
  if (tid < 16) {
    float s = 0.f;
    for (int v = 0; v < 64; ++v) s += Ws[tid][v] * bv[h * 64 + v];
    Fb[h * 512 + og * 16 + tid] = s;
  }
}

// ---------------------------------------------------------------------------
// Kernel 4b: M[o][h*32+k] = sum_c F_h[o][c] * G[c][h*32+k] + Fb[h][o]  (bf16)
// ---------------------------------------------------------------------------
__global__ __launch_bounds__(256) void k_M(
    const float* __restrict__ Gp,   // [n][4][512][256] f32
    const ushort* __restrict__ F,   // [8][512][512] bf16
    const float* __restrict__ Fb,   // [8][512] f32
    ushort* __restrict__ Mbuf)      // [n][512][256] bf16
{
  const int oy = blockIdx.x;   // 4
  const int h  = blockIdx.y;   // 8
  const int n  = blockIdx.z;   // 16
  const int tid = threadIdx.x, wave = tid >> 6, lane = tid & 63;

  __shared__ __align__(16) char smem[32768 + 32768 + 9216];
  ushort* GTs = (ushort*)smem;                  // [32][512] swizzled, 32 KB

  #pragma unroll
  for (int i = 0; i < 16; ++i) {
    int e = tid + i * 256;              // 4096 = 512 c x 8 kq
    int c = e >> 3, kq = e & 7;
    int k = kq * 4;
    const float* gp = Gp + ((size_t)n * 4 * 512 + c) * 256 + h * HK + k;
    f32x4 s = *(const f32x4*)gp;
    s += *(const f32x4*)(gp + (size_t)512 * 256);
    s += *(const f32x4*)(gp + (size_t)2 * 512 * 256);
    s += *(const f32x4*)(gp + (size_t)3 * 512 * 256);
    #pragma unroll
    for (int j = 0; j < 4; ++j) {
      int kk = k + j;
      GTs[kk * 512 + (((c >> 3) ^ (kk & 7)) * 8) + (c & 7)] = f2bf(s[j]);
    }
  }

  const ushort* gA = F + ((size_t)h * 512 + oy * 128) * C_IN;

  #define MSTAGE(buf, k0)                                                        \
    {                                                                            \
      ushort* As_ = (ushort*)(smem + 32768 + (buf) * 16384);                     \
      _Pragma("unroll")                                                          \
      for (int i_ = 0; i_ < 4; ++i_) {                                           \
        int rbase_ = wave * 32 + i_ * 8;                                         \
        int row_ = rbase_ + (lane >> 3);                                         \
        int ss_ = (lane & 7) ^ (row_ & 7);                                       \
        __builtin_amdgcn_global_load_lds(                                        \
            (const __attribute__((address_space(1))) uint32_t*)(gA + (size_t)row_ * C_IN + (k0) + ss_ * 8), \
            (__attribute__((address_space(3))) uint32_t*)(As_ + rbase_ * 64),    \
            16, 0, 0);                                                           \
      }                                                                          \
    }

  f32x4 acc[2][2] = {};

  MSTAGE(0, 0)
  __syncthreads();

  const int nt = C_IN / 64;   // 8
  for (int t = 0; t < nt; ++t) {
    if (t < nt - 1) MSTAGE((t + 1) & 1, (t + 1) * 64)
    ushort* As = (ushort*)(smem + 32768 + (t & 1) * 16384);
    __builtin_amdgcn_s_setprio(1);
    #pragma unroll
    for (int ks = 0; ks < 2; ++ks) {
      s16x8 af[2], bfr[2];
      #pragma unroll
      for (int m = 0; m < 2; ++m) {
        int row = wave * 32 + m * 16 + (lane & 15);
        int slot = (ks * 4 + (lane >> 4)) ^ (row & 7);
        af[m] = *(const s16x8*)&As[row * 64 + slot * 8];
      }
      #pragma unroll
      for (int nf = 0; nf < 2; ++nf) {
        int kr = nf * 16 + (lane & 15);
        int slot = (t * 8 + ks * 4 + (lane >> 4)) ^ (kr & 7);
        bfr[nf] = *(const s16x8*)&GTs[kr * 512 + slot * 8];
      }
      #pragma unroll
      for (int m = 0; m < 2; ++m)
        #pragma unroll
        for (int nf = 0; nf < 2; ++nf)
          acc[m][nf] = __builtin_amdgcn_mfma_f32_16x16x32_bf16(af[m], bfr[nf], acc[m][nf], 0, 0, 0);
    }
    __builtin_amdgcn_s_setprio(0);
    __syncthreads();
  }
  #undef MSTAGE

  float* ep = (float*)(smem + 65536) + wave * (16 * 36);
  const int erow = lane >> 4;
  const int ecol = lane & 15;
  #pragma unroll
  for (int m = 0; m < 2; ++m) {
    #pragma unroll
    for (int nf = 0; nf < 2; ++nf)
      #pragma unroll
      for (int r = 0; r < 4; ++r)
        ep[(erow * 4 + r) * 36 + nf * 16 + ecol] = acc[m][nf][r];
    #pragma unroll
    for (int p = 0; p < 2; ++p) {
      int row16 = p * 8 + (lane >> 3);
      int c4 = (lane & 7) * 4;
      f32x4 v = *(const f32x4*)&ep[row16 * 36 + c4];
      int o = oy * 128 + wave * 32 + m * 16 + row16;
      float fb = Fb[h * 512 + o];
      uint2 pk;
      pk.x = (uint32_t)f2bf(v[0] + fb) | ((uint32_t)f2bf(v[1] + fb) << 16);
      pk.y = (uint32_t)f2bf(v[2] + fb) | ((uint32_t)f2bf(v[3] + fb) << 16);
      *(uint2*)&Mbuf[((size_t)n * 512 + o) * KC + h * HK + c4] = pk;
    }
  }
}

// ---------------------------------------------------------------------------
// Kernel 5: out = x + be + M @ q_smT via MFMA.
// T14: all 16 per-thread x-residual f32x4 loads hoisted BEFORE the K-loop
// (static-indexed xpre[4][4]) so the 134 MB x-read overlaps staging+MFMA.
// ---------------------------------------------------------------------------
#define BM 128
#define BN 128
#define BK 32

__global__ __launch_bounds__(256) void k_final_mfma(
    const ushort* __restrict__ Mb,   // [n][512][256] bf16
    const ushort* __restrict__ qT,   // [n][4096][256] bf16
    const float* __restrict__ x,
    const float* __restrict__ be,
    float* __restrict__ out)
{
  const int n  = blockIdx.z;
  const int oy = blockIdx.y;   // 4
  const int lx = blockIdx.x;   // 32
  const int tid  = threadIdx.x;
  const int wave = tid >> 6, lane = tid & 63;
  const int wr = wave >> 1, wc = wave & 1;

  __shared__ __align__(16) char smem[32768 + 17408];

  f32x4 acc[4][4] = {};

  const ushort* gA = Mb + ((size_t)n * 512 + oy * BM) * KC;
  const ushort* gB = qT + ((size_t)n * L + lx * BN) * KC;

  const int r0 = wave * 32;
  const int lrow = lane >> 2;
  const int erow = lane >> 4;
  const int ecol = lane & 15;

  // ---- T14 prefetch: residual x loads issued before the K-loop ----
  const float* xp = x + ((size_t)n * 512 + oy * BM + wr * 64) * L
                  + (size_t)lx * BN + wc * 64;
  f32x4 xpre[4][4];
  #pragma unroll
  for (int m = 0; m < 4; ++m)
    #pragma unroll
    for (int p = 0; p < 4; ++p)
      xpre[m][p] = *(const f32x4*)&xp[(size_t)(m * 16 + p * 4 + erow) * L + ecol * 4];

  #define FSTAGE(buf, k0)                                                        \
    {                                                                            \
      ushort* As_ = (ushort*)(smem + (buf) * 16384);                             \
      ushort* Bs_ = (ushort*)(smem + (buf) * 16384 + 8192);                      \
      _Pragma("unroll")                                                          \
      for (int i_ = 0; i_ < 2; ++i_) {                                           \
        int row_ = r0 + i_ * 16 + lrow;                                          \
        int ss_ = (lane & 3) ^ ((row_ >> 1) & 3);                                \
        __builtin_amdgcn_global_load_lds(                                        \
            (const __attribute__((address_space(1))) uint32_t*)(gA + (size_t)row_ * KC + (k0) + ss_ * 8), \
            (__attribute__((address_space(3))) uint32_t*)(As_ + (r0 + i_ * 16) * BK), \
            16, 0, 0);                                                           \
        __builtin_amdgcn_global_load_lds(                                        \
            (const __attribute__((address_space(1))) uint32_t*)(gB + (size_t)row_ * KC + (k0) + ss_ * 8), \
            (__attribute__((address_space(3))) uint32_t*)(Bs_ + (r0 + i_ * 16) * BK), \
            16, 0, 0);                                                           \
      }                                                                          \
    }

  FSTAGE(0, 0)
  __syncthreads();

  const int nt = KC / BK;   // 8
  for (int t = 0; t < nt; ++t) {
    if (t < nt - 1) FSTAGE((t + 1) & 1, (t + 1) * BK)
    ushort* As = (ushort*)(smem + (t & 1) * 16384);
    ushort* Bs = (ushort*)(smem + (t & 1) * 16384 + 8192);
    s16x8 af[4], bfr[4];
    #pragma unroll
    for (int m = 0; m < 4; ++m) {
      int row = wr * 64 + m * 16 + (lane & 15);
      int slot = (lane >> 4) ^ ((row >> 1) & 3);
      af[m] = *(const s16x8*)&As[row * BK + slot * 8];
    }
    #pragma unroll
    for (int nn = 0; nn < 4; ++nn) {
      int row = wc * 64 + nn * 16 + (lane & 15);
      int slot = (lane >> 4) ^ ((row >> 1) & 3);
      bfr[nn] = *(const s16x8*)&Bs[row * BK + slot * 8];
    }
    __builtin_amdgcn_s_setprio(1);
    #pragma unroll
    for (int m = 0; m < 4; ++m)
      #pragma unroll
      for (int nn = 0; nn < 4; ++nn)
        acc[m][nn] = __builtin_amdgcn_mfma_f32_16x16x32_bf16(af[m], bfr[nn], acc[m][nn], 0, 0, 0);
    __builtin_amdgcn_s_setprio(0);
    __syncthreads();
  }
  #undef FSTAGE

  float* ep = (float*)(smem + 32768) + wave * (16 * 68);
  const float* bias = be + oy * BM + wr * 64;
  float* op = out + ((size_t)n * 512 + oy * BM + wr * 64) * L
            + (size_t)lx * BN + wc * 64;
  #pragma unroll
  for (int m = 0; m < 4; ++m) {
    #pragma unroll
    for (int nn = 0; nn < 4; ++nn)
      #pragma unroll
      for (int r = 0; r < 4; ++r)
        ep[(erow * 4 + r) * 68 + nn * 16 + ecol] = acc[m][nn][r];
    #pragma unroll
    for (int p = 0; p < 4; ++p) {
      int row = p * 4 + erow;
      f32x4 v = *(const f32x4*)&ep[row * 68 + ecol * 4];
      float bo = bias[m * 16 + row];
      v = v + xpre[m][p] + bo;
      *(f32x4*)&op[(size_t)(m * 16 + row) * L + ecol * 4] = v;
    }
  }
}

// ---------------------------------------------------------------------------
extern "C" void kernel_launch(void* const* d_in, const int* in_sizes, int n_in,
                              void* d_out, int out_size, void* d_ws, size_t ws_size,
                              hipStream_t stream)
{
  const float* x  = (const float*)d_in[0];
  const float* Wk = (const float*)d_in[1];
  const float* bk = (const float*)d_in[2];
  const float* Wq = (const float*)d_in[3];
  const float* bq = (const float*)d_in[4];
  const float* Wv = (const float*)d_in[5];
  const float* bv = (const float*)d_in[6];
  const float* We = (const float*)d_in[7];
  const float* be = (const float*)d_in[8];
  float* out = (float*)d_out;

  char* ws = (char*)d_ws;
  size_t off = 0;
  ushort* Kbuf = (ushort*)(ws + off); off += (size_t)N_BATCH * 256 * L * 2;        // 33.6 MB
  ushort* xb   = (ushort*)(ws + off); off += (size_t)N_BATCH * C_IN * L * 2;       // 67.1 MB
  ushort* Wb   = (ushort*)(ws + off); off += (size_t)512 * C_IN * 2;               // 0.5 MB
  float*  bb   = (float*)(ws + off);  off += (size_t)512 * 4;
  float*  kmax = (float*)(ws + off);  off += (size_t)N_BATCH * KC * 4;
  float*  kinv = (float*)(ws + off);  off += (size_t)N_BATCH * KC * 4;
  ushort* qT   = (ushort*)(ws + off); off += (size_t)N_BATCH * L * KC * 2;         // 33.6 MB
  float*  Gp   = (float*)(ws + off);  off += (size_t)N_BATCH * 4 * 512 * 256 * 4;  // 33.6 MB
  ushort* Fbuf = (ushort*)(ws + off); off += (size_t)NH * 512 * C_IN * 2;          // 4.2 MB
  float*  Fb   = (float*)(ws + off);  off += (size_t)NH * 512 * 4;
  ushort* Mbuf = (ushort*)(ws + off); off += (size_t)N_BATCH * 512 * KC * 2;       // 4.2 MB

  (void)hipFuncSetAttribute((const void*)k_kq_mfma,
                            hipFuncAttributeMaxDynamicSharedMemorySize, 131072);
  (void)hipFuncSetAttribute((const void*)k_G,
                            hipFuncAttributeMaxDynamicSharedMemorySize, 98304);

  k_prep_w<<<dim3(512), 256, 0, stream>>>(Wk, bk, Wq, bq, Wb, bb);
  k_F<<<dim3(NH, 32), 256, 0, stream>>>(Wv, bv, We, Fbuf, Fb);
  k_prep_xb<<<dim3(16384), 256, 0, stream>>>(x, xb);
  k_kq_mfma<<<dim3(16, 2, N_BATCH), 512, 131072, stream>>>(Wb, xb, bb, Kbuf, qT);
  k_kstats3<<<dim3(KC, N_BATCH), 256, 0, stream>>>(Kbuf, kmax, kinv);
  k_G<<<dim3(4, 4, N_BATCH), 512, 98304, stream>>>(xb, Kbuf, kmax, kinv, Gp);
  k_M<<<dim3(4, NH, N_BATCH), 256, 0, stream>>>(Gp, Fbuf, Fb, Mbuf);
  k_final_mfma<<<dim3(32, 4, N_BATCH), 256, 0, stream>>>(Mbuf, qT, x, be, out);
}

// Round 15
// 240.402 us; speedup vs baseline: 1.0530x; 1.0530x over previous
//
#include <hip/hip_runtime.h>
#include <cstddef>
#include <cstdint>

#define N_BATCH 16
#define C_IN    512
#define L       4096
#define KC      256
#define VC      512
#define NH      8
#define HK      32   // KC/NH
#define HV      64   // VC/NH

using f32x4 = __attribute__((ext_vector_type(4))) float;
using s16x8 = __attribute__((ext_vector_type(8))) short;
using s16x4 = __attribute__((ext_vector_type(4))) short;
using u32x2 = __attribute__((ext_vector_type(2))) unsigned int;

// round-to-nearest-even fp32 -> bf16 bits
static __device__ inline ushort f2bf(float f) {
  uint32_t u = __float_as_uint(f);
  uint32_t r = (u + 0x7FFFu + ((u >> 16) & 1u)) >> 16;
  return (ushort)r;
}
static __device__ inline float bf2f(ushort u) {
  return __uint_as_float((uint32_t)u << 16);
}
static __device__ inline s16x8 mk8(u32x2 lo, u32x2 hi) {
  s16x4 a = __builtin_bit_cast(s16x4, lo);
  s16x4 b = __builtin_bit_cast(s16x4, hi);
  return __builtin_shufflevector(a, b, 0, 1, 2, 3, 4, 5, 6, 7);
}

// ---------------------------------------------------------------------------
// Prep 1: bf16 weight matrix Wb[512][512] (rows 0..255 K, 256..511 Q) + bias
// ---------------------------------------------------------------------------
__global__ __launch_bounds__(256) void k_prep_w(
    const float* __restrict__ Wk, const float* __restrict__ bk,
    const float* __restrict__ Wq, const float* __restrict__ bq,
    ushort* __restrict__ Wb, float* __restrict__ bb)
{
  const int o = blockIdx.x;          // 512
  const float* src; const float* bsrc; int oo;
  if (o < 256) { src = Wk + (size_t)o * C_IN;         bsrc = bk; oo = o; }
  else         { src = Wq + (size_t)(o - 256) * C_IN; bsrc = bq; oo = o - 256; }
  const int t = threadIdx.x;
  Wb[(size_t)o * C_IN + t * 2]     = f2bf(src[t * 2]);
  Wb[(size_t)o * C_IN + t * 2 + 1] = f2bf(src[t * 2 + 1]);
  if (t == 0) bb[o] = bsrc[oo];
}

// ---------------------------------------------------------------------------
// Prep 2: streaming cast x (n,512,4096) f32 -> xb bf16 (same layout).
// ---------------------------------------------------------------------------
__global__ __launch_bounds__(256) void k_prep_xb(const float* __restrict__ x,
                                                 ushort* __restrict__ xb)
{
  size_t i = ((size_t)blockIdx.x * 256 + threadIdx.x) * 8;
  f32x4 a = *(const f32x4*)(x + i);
  f32x4 b = *(const f32x4*)(x + i + 4);
  s16x8 w;
  #pragma unroll
  for (int j = 0; j < 4; ++j) {
    w[j]     = (short)f2bf(a[j]);
    w[j + 4] = (short)f2bf(b[j]);
  }
  *(s16x8*)(xb + i) = w;
}

// ---------------------------------------------------------------------------
// Kernel 1: [K;Q] = Wb @ x + bias, bf16 MFMA, 256x256 tile, BK=64, 8 waves.
// A = Wb via swizzled gload_lds; B = xb subtiled LDS + ds_read_b64_tr_b16.
// oy=0 -> Kbuf; oy=1 -> fused channel softmax -> qT.  (round-13 proven)
// ---------------------------------------------------------------------------
#define QBM 256
#define QBN 256
#define QBK 64

#define TRRD(dst, off_lit)                                                       \
  asm volatile("ds_read_b64_tr_b16 %0, %1 offset:" #off_lit                      \
               : "=v"(dst) : "v"(trp));

__global__ __launch_bounds__(512) void k_kq_mfma(
    const ushort* __restrict__ Wb,   // [512][512] bf16
    const ushort* __restrict__ xb,   // [n][512][4096] bf16
    const float* __restrict__ bb,    // [512]
    ushort* __restrict__ Kbuf,       // [n][256][4096] bf16
    ushort* __restrict__ qT)         // [n][4096][256] bf16 (normalized Q^T)
{
  extern __shared__ __align__(16) char smem[];
  const int n  = blockIdx.z;
  const int oy = blockIdx.y;   // 0 = K rows, 1 = Q rows
  const int lx = blockIdx.x;   // 16 col tiles of 256
  const int tid  = threadIdx.x;
  const int wave = tid >> 6, lane = tid & 63;
  const int wr = wave >> 2, wc = wave & 3;   // 2 x 4

  f32x4 acc[8][4] = {};

  const ushort* gA = Wb + (size_t)(oy * QBM) * C_IN;
  const ushort* gX = xb + (size_t)n * C_IN * L + (size_t)lx * QBN;  // + c*L + l

  #define ASTG(buf, k0)                                                          \
    {                                                                            \
      ushort* As_ = (ushort*)(smem + (buf) * 65536);                             \
      _Pragma("unroll")                                                          \
      for (int i_ = 0; i_ < 4; ++i_) {                                           \
        int rbase_ = wave * 32 + i_ * 8;                                         \
        int row_ = rbase_ + (lane >> 3);                                         \
        int ss_ = (lane & 7) ^ (row_ & 7);                                       \
        __builtin_amdgcn_global_load_lds(                                        \
            (const __attribute__((address_space(1))) uint32_t*)(gA + (size_t)row_ * C_IN + (k0) + ss_ * 8), \
            (__attribute__((address_space(3))) uint32_t*)(As_ + rbase_ * QBK),   \
            16, 0, 0);                                                           \
      }                                                                          \
    }

  #define BSTG(buf, k0)                                                          \
    {                                                                            \
      ushort* Bs_ = (ushort*)(smem + (buf) * 65536 + 32768);                     \
      _Pragma("unroll")                                                          \
      for (int i_ = 0; i_ < 4; ++i_) {                                           \
        int chunk_ = i_ * 512 + tid;                                             \
        int lh_ = chunk_ & 1, crow_ = (chunk_ >> 1) & 3;                         \
        int c4_ = (chunk_ >> 3) & 15, l16_ = chunk_ >> 7;                        \
        __builtin_amdgcn_global_load_lds(                                        \
            (const __attribute__((address_space(1))) uint32_t*)(gX + (size_t)((k0) + c4_ * 4 + crow_) * L + l16_ * 16 + lh_ * 8), \
            (__attribute__((address_space(3))) uint32_t*)(Bs_ + (i_ * 512 + wave * 64) * 8), \
            16, 0, 0);                                                           \
      }                                                                          \
    }

  ASTG(0, 0)
  BSTG(0, 0)
  __syncthreads();

  const int nt = C_IN / QBK;   // 8
  for (int t = 0; t < nt; ++t) {
    if (t < nt - 1) {
      ASTG((t + 1) & 1, (t + 1) * QBK)
      BSTG((t + 1) & 1, (t + 1) * QBK)
    }
    ushort* As = (ushort*)(smem + (t & 1) * 65536);
    ushort* Bs = (ushort*)(smem + (t & 1) * 65536 + 32768);
    __builtin_amdgcn_s_setprio(1);
    #pragma unroll
    for (int ks = 0; ks < 2; ++ks) {
      s16x8 af[8];
      #pragma unroll
      for (int m = 0; m < 8; ++m) {
        int row = wr * 128 + m * 16 + (lane & 15);
        int slot = (ks * 4 + (lane >> 4)) ^ (row & 7);
        af[m] = *(const s16x8*)&As[row * QBK + slot * 8];
      }
      const int trb = wc * 8192 + ks * 1024 + (lane >> 4) * 256 + (lane & 15) * 2;
      __attribute__((address_space(3))) char* trp =
          (__attribute__((address_space(3))) char*)Bs + trb;
      u32x2 lo0, hi0, lo1, hi1, lo2, hi2, lo3, hi3;
      TRRD(lo0, 0)    TRRD(hi0, 128)
      TRRD(lo1, 2048) TRRD(hi1, 2176)
      TRRD(lo2, 4096) TRRD(hi2, 4224)
      TRRD(lo3, 6144) TRRD(hi3, 6272)
      asm volatile("s_waitcnt lgkmcnt(0)" ::: "memory");
      __builtin_amdgcn_sched_barrier(0);
      s16x8 bfr[4];
      bfr[0] = mk8(lo0, hi0);
      bfr[1] = mk8(lo1, hi1);
      bfr[2] = mk8(lo2, hi2);
      bfr[3] = mk8(lo3, hi3);
      #pragma unroll
      for (int m = 0; m < 8; ++m)
        #pragma unroll
        for (int nn = 0; nn < 4; ++nn)
          acc[m][nn] = __builtin_amdgcn_mfma_f32_16x16x32_bf16(af[m], bfr[nn], acc[m][nn], 0, 0, 0);
    }
    __builtin_amdgcn_s_setprio(0);
    __syncthreads();
  }
  #undef ASTG
  #undef BSTG

  if (oy == 0) {
    float* ep = (float*)smem + wave * (16 * 68);
    const int erow = lane >> 4;
    const int ecol = lane & 15;
    const float* bias = bb + wr * 128;
    ushort* outp = Kbuf + ((size_t)n * 256 + wr * 128) * L
                 + (size_t)lx * QBN + wc * 64;
    #pragma unroll
    for (int m = 0; m < 8; ++m) {
      #pragma unroll
      for (int nn = 0; nn < 4; ++nn)
        #pragma unroll
        for (int r = 0; r < 4; ++r)
          ep[(erow * 4 + r) * 68 + nn * 16 + ecol] = acc[m][nn][r];
      #pragma unroll
      for (int p = 0; p < 4; ++p) {
        int row = p * 4 + erow;
        f32x4 v = *(const f32x4*)&ep[row * 68 + ecol * 4];
        float bo = bias[m * 16 + row];
        uint2 pk;
        pk.x = (uint32_t)f2bf(v[0] + bo) | ((uint32_t)f2bf(v[1] + bo) << 16);
        pk.y = (uint32_t)f2bf(v[2] + bo) | ((uint32_t)f2bf(v[3] + bo) << 16);
        *(uint2*)&outp[(size_t)(m * 16 + row) * L + ecol * 4] = pk;
      }
    }
  } else {
    const float* bias = bb + 256 + wr * 128;
    ushort* qbase = qT + (size_t)n * L * KC;
    const int g4 = (lane >> 4) * 4;
    #pragma unroll
    for (int hp = 0; hp < 4; ++hp) {
      const int m0 = 2 * hp, m1 = 2 * hp + 1;
      const float b0_0 = bias[m0 * 16 + g4 + 0], b0_1 = bias[m0 * 16 + g4 + 1];
      const float b0_2 = bias[m0 * 16 + g4 + 2], b0_3 = bias[m0 * 16 + g4 + 3];
      const float b1_0 = bias[m1 * 16 + g4 + 0], b1_1 = bias[m1 * 16 + g4 + 1];
      const float b1_2 = bias[m1 * 16 + g4 + 2], b1_3 = bias[m1 * 16 + g4 + 3];
      #pragma unroll
      for (int nn = 0; nn < 4; ++nn) {
        float v0[4], v1[4];
        v0[0] = acc[m0][nn][0] + b0_0; v0[1] = acc[m0][nn][1] + b0_1;
        v0[2] = acc[m0][nn][2] + b0_2; v0[3] = acc[m0][nn][3] + b0_3;
        v1[0] = acc[m1][nn][0] + b1_0; v1[1] = acc[m1][nn][1] + b1_1;
        v1[2] = acc[m1][nn][2] + b1_2; v1[3] = acc[m1][nn][3] + b1_3;
        float mx = fmaxf(fmaxf(fmaxf(v0[0], v0[1]), fmaxf(v0[2], v0[3])),
                         fmaxf(fmaxf(v1[0], v1[1]), fmaxf(v1[2], v1[3])));
        mx = fmaxf(mx, __shfl_xor(mx, 16));
        mx = fmaxf(mx, __shfl_xor(mx, 32));
        float e0[4], e1[4];
        float s = 0.f;
        #pragma unroll
        for (int r = 0; r < 4; ++r) { e0[r] = __expf(v0[r] - mx); s += e0[r]; }
        #pragma unroll
        for (int r = 0; r < 4; ++r) { e1[r] = __expf(v1[r] - mx); s += e1[r]; }
        s += __shfl_xor(s, 16);
        s += __shfl_xor(s, 32);
        float inv = 1.0f / s;
        int l = lx * QBN + wc * 64 + nn * 16 + (lane & 15);
        ushort* dst = qbase + (size_t)l * KC + wr * 128;
        uint2 p0, p1;
        p0.x = (uint32_t)f2bf(e0[0] * inv) | ((uint32_t)f2bf(e0[1] * inv) << 16);
        p0.y = (uint32_t)f2bf(e0[2] * inv) | ((uint32_t)f2bf(e0[3] * inv) << 16);
        p1.x = (uint32_t)f2bf(e1[0] * inv) | ((uint32_t)f2bf(e1[1] * inv) << 16);
        p1.y = (uint32_t)f2bf(e1[2] * inv) | ((uint32_t)f2bf(e1[3] * inv) << 16);
        *(uint2*)&dst[m0 * 16 + g4] = p0;
        *(uint2*)&dst[m1 * 16 + g4] = p1;
      }
    }
  }
}

// ---------------------------------------------------------------------------
// Reductions
// ---------------------------------------------------------------------------
__device__ inline float blockReduceMax(float v, float* red) {
  #pragma unroll
  for (int off = 32; off > 0; off >>= 1)
    v = fmaxf(v, __shfl_down(v, off, 64));
  int tid = threadIdx.x;
  if ((tid & 63) == 0) red[tid >> 6] = v;
  __syncthreads();
  return fmaxf(fmaxf(red[0], red[1]), fmaxf(red[2], red[3]));
}
__device__ inline float blockReduceSum(float v, float* red) {
  #pragma unroll
  for (int off = 32; off > 0; off >>= 1)
    v += __shfl_down(v, off, 64);
  int tid = threadIdx.x;
  if ((tid & 63) == 0) red[tid >> 6] = v;
  __syncthreads();
  return red[0] + red[1] + red[2] + red[3];
}

// ---------------------------------------------------------------------------
// Kernel 2: K softmax stats over L per (n,row) -> kmax, kinv (stats only)
// ---------------------------------------------------------------------------
__global__ __launch_bounds__(256) void k_kstats3(const ushort* __restrict__ Kbuf,
                                                 float* __restrict__ kmax,
                                                 float* __restrict__ kinv)
{
  const int r = blockIdx.x;
  const int n = blockIdx.y;
  const ushort* row = Kbuf + ((size_t)n * 256 + r) * L;
  __shared__ float red1[4];
  __shared__ float red2[4];
  const int tid = threadIdx.x;
  s16x8 a = *(const s16x8*)(row + tid * 16);
  s16x8 b = *(const s16x8*)(row + tid * 16 + 8);
  float v[16];
  #pragma unroll
  for (int j = 0; j < 8; ++j) { v[j] = bf2f((ushort)a[j]); v[8 + j] = bf2f((ushort)b[j]); }
  float m = -3.0e38f;
  #pragma unroll
  for (int j = 0; j < 16; ++j) m = fmaxf(m, v[j]);
  m = blockReduceMax(m, red1);
  float s = 0.f;
  #pragma unroll
  for (int j = 0; j < 16; ++j) s += __expf(v[j] - m);
  s = blockReduceSum(s, red2);
  if (tid == 0) { kmax[n * KC + r] = m; kinv[n * KC + r] = 1.0f / s; }
}

// ---------------------------------------------------------------------------
// Kernel 3: G[c][k] = sum_l x[c,l] * softmax(K)[k,l]  (per n, l-chunk part).
// ---------------------------------------------------------------------------
#define GBK 64

__global__ __launch_bounds__(512) void k_G(
    const ushort* __restrict__ xb,   // [n][512][4096] bf16
    const ushort* __restrict__ Kbuf, // [n][256][4096] bf16
    const float* __restrict__ kmax,
    const float* __restrict__ kinv,
    float* __restrict__ Gp)          // [n][4][512][256] f32
{
  extern __shared__ __align__(16) char smem[];
  const int cm = blockIdx.x;   // 4 c-tiles of 128
  const int lc = blockIdx.y;   // 4 l-chunks of 1024
  const int n  = blockIdx.z;
  const int tid  = threadIdx.x;
  const int wave = tid >> 6, lane = tid & 63;
  const int wr = wave >> 2, wc = wave & 3;   // 2 x 4

  f32x4 acc[4][4] = {};

  const ushort* gxb = xb   + ((size_t)n * C_IN + cm * 128) * L + lc * 1024;
  const ushort* gK  = Kbuf + (size_t)n * 256 * L + lc * 1024;

  const int brow = tid >> 1;
  const int bseg0 = (tid & 1) * 4;
  const float mk = kmax[n * KC + brow];
  const float ik = kinv[n * KC + brow];

  #define ASTAGE(buf, k0)                                                        \
    {                                                                            \
      ushort* As_ = (ushort*)(smem + (buf) * 49152);                             \
      _Pragma("unroll")                                                          \
      for (int i_ = 0; i_ < 2; ++i_) {                                           \
        int rbase_ = wave * 16 + i_ * 8;                                         \
        int row_ = rbase_ + (lane >> 3);                                         \
        int ss_ = (lane & 7) ^ (row_ & 7);                                       \
        __builtin_amdgcn_global_load_lds(                                        \
            (const __attribute__((address_space(1))) uint32_t*)(gxb + (size_t)row_ * L + (k0) + ss_ * 8), \
            (__attribute__((address_space(3))) uint32_t*)(As_ + rbase_ * GBK),   \
            16, 0, 0);                                                           \
      }                                                                          \
    }

  #define BLOAD(k0)                                                              \
    _Pragma("unroll")                                                            \
    for (int i_ = 0; i_ < 4; ++i_)                                               \
      bk[i_] = *(const s16x8*)(gK + (size_t)brow * L + (k0) + (bseg0 + i_) * 8);

  #define BWRITE(buf)                                                            \
    {                                                                            \
      ushort* Bs_ = (ushort*)(smem + (buf) * 49152 + 16384);                     \
      _Pragma("unroll")                                                          \
      for (int i_ = 0; i_ < 4; ++i_) {                                           \
        s16x8 w_;                                                                \
        _Pragma("unroll")                                                        \
        for (int j_ = 0; j_ < 8; ++j_)                                           \
          w_[j_] = (short)f2bf(__expf(bf2f((ushort)bk[i_][j_]) - mk) * ik);      \
        *(s16x8*)&Bs_[brow * GBK + ((bseg0 + i_) ^ (brow & 7)) * 8] = w_;        \
      }                                                                          \
    }

  s16x8 bk[4];

  BLOAD(0)
  ASTAGE(0, 0)
  BWRITE(0)
  __syncthreads();

  const int nt = 1024 / GBK;   // 16
  for (int t = 0; t < nt; ++t) {
    const int cb = t & 1, nb = cb ^ 1;
    if (t < nt - 1) {
      BLOAD((t + 1) * GBK)
      ASTAGE(nb, (t + 1) * GBK)
    }
    ushort* As = (ushort*)(smem + cb * 49152);
    ushort* Bs = (ushort*)(smem + cb * 49152 + 16384);
    __builtin_amdgcn_s_setprio(1);
    #pragma unroll
    for (int ks = 0; ks < 2; ++ks) {
      s16x8 af[4], bfr[4];
      #pragma unroll
      for (int m = 0; m < 4; ++m) {
        int row = wr * 64 + m * 16 + (lane & 15);
        int slot = (ks * 4 + (lane >> 4)) ^ (row & 7);
        af[m] = *(const s16x8*)&As[row * GBK + slot * 8];
      }
      #pragma unroll
      for (int nn = 0; nn < 4; ++nn) {
        int row = wc * 64 + nn * 16 + (lane & 15);
        int slot = (ks * 4 + (lane >> 4)) ^ (row & 7);
        bfr[nn] = *(const s16x8*)&Bs[row * GBK + slot * 8];
      }
      #pragma unroll
      for (int m = 0; m < 4; ++m)
        #pragma unroll
        for (int nn = 0; nn < 4; ++nn)
          acc[m][nn] = __builtin_amdgcn_mfma_f32_16x16x32_bf16(af[m], bfr[nn], acc[m][nn], 0, 0, 0);
    }
    __builtin_amdgcn_s_setprio(0);
    if (t < nt - 1) BWRITE(nb)
    __syncthreads();
  }
  #undef ASTAGE
  #undef BLOAD
  #undef BWRITE

  float* ep = (float*)smem + wave * (16 * 68);
  const int erow = lane >> 4;
  const int ecol = lane & 15;
  float* op = Gp + (((size_t)n * 4 + lc) * 512 + cm * 128 + wr * 64) * 256 + wc * 64;
  #pragma unroll
  for (int m = 0; m < 4; ++m) {
    #pragma unroll
    for (int nn = 0; nn < 4; ++nn)
      #pragma unroll
      for (int r = 0; r < 4; ++r)
        ep[(erow * 4 + r) * 68 + nn * 16 + ecol] = acc[m][nn][r];
    #pragma unroll
    for (int p = 0; p < 4; ++p) {
      int row16 = p * 4 + erow;
      f32x4 v = *(const f32x4*)&ep[row16 * 68 + ecol * 4];
      *(f32x4*)&op[(size_t)(m * 16 + row16) * 256 + ecol * 4] = v;
    }
  }
}

// ---------------------------------------------------------------------------
// Kernel 4a: F[h][o][c] = sum_v We[o][h*64+v] * Wv[h*64+v][c]  (bf16)
//            Fb[h][o]   = sum_v We[o][h*64+v] * bv[h*64+v]     (f32)
// ---------------------------------------------------------------------------
__global__ __launch_bounds__(256) void k_F(
    const float* __restrict__ Wv, const float* __restrict__ bv,
    const float* __restrict__ We,
    ushort* __restrict__ F, float* __restrict__ Fb)
{
  const int h  = blockIdx.x;   // 8
  const int og = blockIdx.y;   // 32
  const int tid = threadIdx.x;
  __shared__ float Ws[16][64];
  #pragma unroll
  for (int i = 0; i < 4; ++i) {
    int e = tid + i * 256;
    int o = e >> 6, v = e & 63;
    Ws[o][v] = We[(size_t)(og * 16 + o) * VC + h * 64 + v];
  }
  __syncthreads();
  const int c2 = tid * 2;
  float acc[16][2] = {};
  for (int v = 0; v < 64; ++v) {
    float2 w = *(const float2*)&Wv[(size_t)(h * 64 + v) * C_IN + c2];
    #pragma unroll
    for (int o = 0; o < 16; ++o) {
      acc[o][0] += Ws[o][v] * w.x;
      acc[o][1] += Ws[o][v] * w.y;
    }
  }
  ushort* Fh = F + ((size_t)h * 512 + og * 16) * C_IN;
  #pragma unroll
  for (int o = 0; o < 16; ++o) {
    uint32_t pk = (uint32_t)f2bf(acc[o][0]) | ((uint32_t)f2bf(acc[o][1]) << 16);
    *(uint32_t*)&Fh[(size_t)o * C_IN + c2] = pk;
  }
  if (tid < 16) {
    float s = 0.f;
    for (int v = 0; v < 64; ++v) s += Ws[tid][v] * bv[h * 64 + v];
    Fb[h * 512 + og * 16 + tid] = s;
  }
}

// ---------------------------------------------------------------------------
// Kernel 4b: M[o][h*32+k] = sum_c F_h[o][c] * G[c][h*32+k] + Fb[h][o]  (bf16)
// ---------------------------------------------------------------------------
__global__ __launch_bounds__(256) void k_M(
    const float* __restrict__ Gp,   // [n][4][512][256] f32
    const ushort* __restrict__ F,   // [8][512][512] bf16
    const float* __restrict__ Fb,   // [8][512] f32
    ushort* __restrict__ Mbuf)      // [n][512][256] bf16
{
  const int oy = blockIdx.x;   // 4
  const int h  = blockIdx.y;   // 8
  const int n  = blockIdx.z;   // 16
  const int tid = threadIdx.x, wave = tid >> 6, lane = tid & 63;

  __shared__ __align__(16) char smem[32768 + 32768 + 9216];
  ushort* GTs = (ushort*)smem;                  // [32][512] swizzled, 32 KB

  #pragma unroll
  for (int i = 0; i < 16; ++i) {
    int e = tid + i * 256;              // 4096 = 512 c x 8 kq
    int c = e >> 3, kq = e & 7;
    int k = kq * 4;
    const float* gp = Gp + ((size_t)n * 4 * 512 + c) * 256 + h * HK + k;
    f32x4 s = *(const f32x4*)gp;
    s += *(const f32x4*)(gp + (size_t)512 * 256);
    s += *(const f32x4*)(gp + (size_t)2 * 512 * 256);
    s += *(const f32x4*)(gp + (size_t)3 * 512 * 256);
    #pragma unroll
    for (int j = 0; j < 4; ++j) {
      int kk = k + j;
      GTs[kk * 512 + (((c >> 3) ^ (kk & 7)) * 8) + (c & 7)] = f2bf(s[j]);
    }
  }

  const ushort* gA = F + ((size_t)h * 512 + oy * 128) * C_IN;

  #define MSTAGE(buf, k0)                                                        \
    {                                                                            \
      ushort* As_ = (ushort*)(smem + 32768 + (buf) * 16384);                     \
      _Pragma("unroll")                                                          \
      for (int i_ = 0; i_ < 4; ++i_) {                                           \
        int rbase_ = wave * 32 + i_ * 8;                                         \
        int row_ = rbase_ + (lane >> 3);                                         \
        int ss_ = (lane & 7) ^ (row_ & 7);                                       \
        __builtin_amdgcn_global_load_lds(                                        \
            (const __attribute__((address_space(1))) uint32_t*)(gA + (size_t)row_ * C_IN + (k0) + ss_ * 8), \
            (__attribute__((address_space(3))) uint32_t*)(As_ + rbase_ * 64),    \
            16, 0, 0);                                                           \
      }                                                                          \
    }

  f32x4 acc[2][2] = {};

  MSTAGE(0, 0)
  __syncthreads();

  const int nt = C_IN / 64;   // 8
  for (int t = 0; t < nt; ++t) {
    if (t < nt - 1) MSTAGE((t + 1) & 1, (t + 1) * 64)
    ushort* As = (ushort*)(smem + 32768 + (t & 1) * 16384);
    __builtin_amdgcn_s_setprio(1);
    #pragma unroll
    for (int ks = 0; ks < 2; ++ks) {
      s16x8 af[2], bfr[2];
      #pragma unroll
      for (int m = 0; m < 2; ++m) {
        int row = wave * 32 + m * 16 + (lane & 15);
        int slot = (ks * 4 + (lane >> 4)) ^ (row & 7);
        af[m] = *(const s16x8*)&As[row * 64 + slot * 8];
      }
      #pragma unroll
      for (int nf = 0; nf < 2; ++nf) {
        int kr = nf * 16 + (lane & 15);
        int slot = (t * 8 + ks * 4 + (lane >> 4)) ^ (kr & 7);
        bfr[nf] = *(const s16x8*)&GTs[kr * 512 + slot * 8];
      }
      #pragma unroll
      for (int m = 0; m < 2; ++m)
        #pragma unroll
        for (int nf = 0; nf < 2; ++nf)
          acc[m][nf] = __builtin_amdgcn_mfma_f32_16x16x32_bf16(af[m], bfr[nf], acc[m][nf], 0, 0, 0);
    }
    __builtin_amdgcn_s_setprio(0);
    __syncthreads();
  }
  #undef MSTAGE

  float* ep = (float*)(smem + 65536) + wave * (16 * 36);
  const int erow = lane >> 4;
  const int ecol = lane & 15;
  #pragma unroll
  for (int m = 0; m < 2; ++m) {
    #pragma unroll
    for (int nf = 0; nf < 2; ++nf)
      #pragma unroll
      for (int r = 0; r < 4; ++r)
        ep[(erow * 4 + r) * 36 + nf * 16 + ecol] = acc[m][nf][r];
    #pragma unroll
    for (int p = 0; p < 2; ++p) {
      int row16 = p * 8 + (lane >> 3);
      int c4 = (lane & 7) * 4;
      f32x4 v = *(const f32x4*)&ep[row16 * 36 + c4];
      int o = oy * 128 + wave * 32 + m * 16 + row16;
      float fb = Fb[h * 512 + o];
      uint2 pk;
      pk.x = (uint32_t)f2bf(v[0] + fb) | ((uint32_t)f2bf(v[1] + fb) << 16);
      pk.y = (uint32_t)f2bf(v[2] + fb) | ((uint32_t)f2bf(v[3] + fb) << 16);
      *(uint2*)&Mbuf[((size_t)n * 512 + o) * KC + h * HK + c4] = pk;
    }
  }
}

// ---------------------------------------------------------------------------
// Kernel 5: out = x + be + M @ q_smT via MFMA.  Round-13 K-loop; epilogue
// issues ALL 16 x-residual f32x4 loads upfront (16-deep MLP, no barrier in
// between) then overlaps the wave-private LDS transpose staging with them.
// ---------------------------------------------------------------------------
#define BM 128
#define BN 128
#define BK 32

__global__ __launch_bounds__(256) void k_final_mfma(
    const ushort* __restrict__ Mb,   // [n][512][256] bf16
    const ushort* __restrict__ qT,   // [n][4096][256] bf16
    const float* __restrict__ x,
    const float* __restrict__ be,
    float* __restrict__ out)
{
  const int n  = blockIdx.z;
  const int oy = blockIdx.y;   // 4
  const int lx = blockIdx.x;   // 32
  const int tid  = threadIdx.x;
  const int wave = tid >> 6, lane = tid & 63;
  const int wr = wave >> 1, wc = wave & 1;

  __shared__ __align__(16) char smem[32768 + 17408];

  f32x4 acc[4][4] = {};

  const ushort* gA = Mb + ((size_t)n * 512 + oy * BM) * KC;
  const ushort* gB = qT + ((size_t)n * L + lx * BN) * KC;

  const int r0 = wave * 32;
  const int lrow = lane >> 2;

  #define FSTAGE(buf, k0)                                                        \
    {                                                                            \
      ushort* As_ = (ushort*)(smem + (buf) * 16384);                             \
      ushort* Bs_ = (ushort*)(smem + (buf) * 16384 + 8192);                      \
      _Pragma("unroll")                                                          \
      for (int i_ = 0; i_ < 2; ++i_) {                                           \
        int row_ = r0 + i_ * 16 + lrow;                                          \
        int ss_ = (lane & 3) ^ ((row_ >> 1) & 3);                                \
        __builtin_amdgcn_global_load_lds(                                        \
            (const __attribute__((address_space(1))) uint32_t*)(gA + (size_t)row_ * KC + (k0) + ss_ * 8), \
            (__attribute__((address_space(3))) uint32_t*)(As_ + (r0 + i_ * 16) * BK), \
            16, 0, 0);                                                           \
        __builtin_amdgcn_global_load_lds(                                        \
            (const __attribute__((address_space(1))) uint32_t*)(gB + (size_t)row_ * KC + (k0) + ss_ * 8), \
            (__attribute__((address_space(3))) uint32_t*)(Bs_ + (r0 + i_ * 16) * BK), \
            16, 0, 0);                                                           \
      }                                                                          \
    }

  FSTAGE(0, 0)
  __syncthreads();

  const int nt = KC / BK;   // 8
  for (int t = 0; t < nt; ++t) {
    if (t < nt - 1) FSTAGE((t + 1) & 1, (t + 1) * BK)
    ushort* As = (ushort*)(smem + (t & 1) * 16384);
    ushort* Bs = (ushort*)(smem + (t & 1) * 16384 + 8192);
    s16x8 af[4], bfr[4];
    #pragma unroll
    for (int m = 0; m < 4; ++m) {
      int row = wr * 64 + m * 16 + (lane & 15);
      int slot = (lane >> 4) ^ ((row >> 1) & 3);
      af[m] = *(const s16x8*)&As[row * BK + slot * 8];
    }
    #pragma unroll
    for (int nn = 0; nn < 4; ++nn) {
      int row = wc * 64 + nn * 16 + (lane & 15);
      int slot = (lane >> 4) ^ ((row >> 1) & 3);
      bfr[nn] = *(const s16x8*)&Bs[row * BK + slot * 8];
    }
    __builtin_amdgcn_s_setprio(1);
    #pragma unroll
    for (int m = 0; m < 4; ++m)
      #pragma unroll
      for (int nn = 0; nn < 4; ++nn)
        acc[m][nn] = __builtin_amdgcn_mfma_f32_16x16x32_bf16(af[m], bfr[nn], acc[m][nn], 0, 0, 0);
    __builtin_amdgcn_s_setprio(0);
    __syncthreads();
  }
  #undef FSTAGE

  // Epilogue: issue all residual x loads first (16-deep MLP), then overlap
  // the wave-private LDS transpose with them.  No barriers -> no drain.
  const int erow = lane >> 4;
  const int ecol = lane & 15;
  const float* xp = x + ((size_t)n * 512 + oy * BM + wr * 64) * L
                  + (size_t)lx * BN + wc * 64;
  f32x4 xpre[4][4];
  #pragma unroll
  for (int m = 0; m < 4; ++m)
    #pragma unroll
    for (int p = 0; p < 4; ++p)
      xpre[m][p] = *(const f32x4*)&xp[(size_t)(m * 16 + p * 4 + erow) * L + ecol * 4];

  float* ep = (float*)(smem + 32768) + wave * (16 * 68);
  const float* bias = be + oy * BM + wr * 64;
  float* op = out + ((size_t)n * 512 + oy * BM + wr * 64) * L
            + (size_t)lx * BN + wc * 64;
  #pragma unroll
  for (int m = 0; m < 4; ++m) {
    #pragma unroll
    for (int nn = 0; nn < 4; ++nn)
      #pragma unroll
      for (int r = 0; r < 4; ++r)
        ep[(erow * 4 + r) * 68 + nn * 16 + ecol] = acc[m][nn][r];
    #pragma unroll
    for (int p = 0; p < 4; ++p) {
      int row = p * 4 + erow;
      f32x4 v = *(const f32x4*)&ep[row * 68 + ecol * 4];
      float bo = bias[m * 16 + row];
      v = v + xpre[m][p] + bo;
      *(f32x4*)&op[(size_t)(m * 16 + row) * L + ecol * 4] = v;
    }
  }
}

// ---------------------------------------------------------------------------
extern "C" void kernel_launch(void* const* d_in, const int* in_sizes, int n_in,
                              void* d_out, int out_size, void* d_ws, size_t ws_size,
                              hipStream_t stream)
{
  const float* x  = (const float*)d_in[0];
  const float* Wk = (const float*)d_in[1];
  const float* bk = (const float*)d_in[2];
  const float* Wq = (const float*)d_in[3];
  const float* bq = (const float*)d_in[4];
  const float* Wv = (const float*)d_in[5];
  const float* bv = (const float*)d_in[6];
  const float* We = (const float*)d_in[7];
  const float* be = (const float*)d_in[8];
  float* out = (float*)d_out;

  char* ws = (char*)d_ws;
  size_t off = 0;
  ushort* Kbuf = (ushort*)(ws + off); off += (size_t)N_BATCH * 256 * L * 2;        // 33.6 MB
  ushort* xb   = (ushort*)(ws + off); off += (size_t)N_BATCH * C_IN * L * 2;       // 67.1 MB
  ushort* Wb   = (ushort*)(ws + off); off += (size_t)512 * C_IN * 2;               // 0.5 MB
  float*  bb   = (float*)(ws + off);  off += (size_t)512 * 4;
  float*  kmax = (float*)(ws + off);  off += (size_t)N_BATCH * KC * 4;
  float*  kinv = (float*)(ws + off);  off += (size_t)N_BATCH * KC * 4;
  ushort* qT   = (ushort*)(ws + off); off += (size_t)N_BATCH * L * KC * 2;         // 33.6 MB
  float*  Gp   = (float*)(ws + off);  off += (size_t)N_BATCH * 4 * 512 * 256 * 4;  // 33.6 MB
  ushort* Fbuf = (ushort*)(ws + off); off += (size_t)NH * 512 * C_IN * 2;          // 4.2 MB
  float*  Fb   = (float*)(ws + off);  off += (size_t)NH * 512 * 4;
  ushort* Mbuf = (ushort*)(ws + off); off += (size_t)N_BATCH * 512 * KC * 2;       // 4.2 MB

  (void)hipFuncSetAttribute((const void*)k_kq_mfma,
                            hipFuncAttributeMaxDynamicSharedMemorySize, 131072);
  (void)hipFuncSetAttribute((const void*)k_G,
                            hipFuncAttributeMaxDynamicSharedMemorySize, 98304);

  k_prep_w<<<dim3(512), 256, 0, stream>>>(Wk, bk, Wq, bq, Wb, bb);
  k_F<<<dim3(NH, 32), 256, 0, stream>>>(Wv, bv, We, Fbuf, Fb);
  k_prep_xb<<<dim3(16384), 256, 0, stream>>>(x, xb);
  k_kq_mfma<<<dim3(16, 2, N_BATCH), 512, 131072, stream>>>(Wb, xb, bb, Kbuf, qT);
  k_kstats3<<<dim3(KC, N_BATCH), 256, 0, stream>>>(Kbuf, kmax, kinv);
  k_G<<<dim3(4, 4, N_BATCH), 512, 98304, stream>>>(xb, Kbuf, kmax, kinv, Gp);
  k_M<<<dim3(4, NH, N_BATCH), 256, 0, stream>>>(Gp, Fbuf, Fb, Mbuf);
  k_final_mfma<<<dim3(32, 4, N_BATCH), 256, 0, stream>>>(Mbuf, qT, x, be, out);
}

// Round 16
// 229.412 us; speedup vs baseline: 1.1034x; 1.0479x over previous
//
#include <hip/hip_runtime.h>
#include <cstddef>
#include <cstdint>

#define N_BATCH 16
#define C_IN    512
#define L       4096
#define KC      256
#define VC      512
#define NH      8
#define HK      32   // KC/NH
#define HV      64   // VC/NH

using f32x4 = __attribute__((ext_vector_type(4))) float;
using s16x8 = __attribute__((ext_vector_type(8))) short;
using s16x4 = __attribute__((ext_vector_type(4))) short;
using u32x2 = __attribute__((ext_vector_type(2))) unsigned int;

// round-to-nearest-even fp32 -> bf16 bits
static __device__ inline ushort f2bf(float f) {
  uint32_t u = __float_as_uint(f);
  uint32_t r = (u + 0x7FFFu + ((u >> 16) & 1u)) >> 16;
  return (ushort)r;
}
static __device__ inline float bf2f(ushort u) {
  return __uint_as_float((uint32_t)u << 16);
}
static __device__ inline s16x8 mk8(u32x2 lo, u32x2 hi) {
  s16x4 a = __builtin_bit_cast(s16x4, lo);
  s16x4 b = __builtin_bit_cast(s16x4, hi);
  return __builtin_shufflevector(a, b, 0, 1, 2, 3, 4, 5, 6, 7);
}

// bijective XCD swizzle (nwg % 8 == 0): logical wgid such that
// logical-adjacent blocks land on the same XCD (m204).
static __device__ inline int xcd_swz(int orig, int q) {
  return (orig & 7) * q + (orig >> 3);
}

// ---------------------------------------------------------------------------
// Prep 1: bf16 weight matrix Wb[512][512] (rows 0..255 K, 256..511 Q) + bias
// ---------------------------------------------------------------------------
__global__ __launch_bounds__(256) void k_prep_w(
    const float* __restrict__ Wk, const float* __restrict__ bk,
    const float* __restrict__ Wq, const float* __restrict__ bq,
    ushort* __restrict__ Wb, float* __restrict__ bb)
{
  const int o = blockIdx.x;          // 512
  const float* src; const float* bsrc; int oo;
  if (o < 256) { src = Wk + (size_t)o * C_IN;         bsrc = bk; oo = o; }
  else         { src = Wq + (size_t)(o - 256) * C_IN; bsrc = bq; oo = o - 256; }
  const int t = threadIdx.x;
  Wb[(size_t)o * C_IN + t * 2]     = f2bf(src[t * 2]);
  Wb[(size_t)o * C_IN + t * 2 + 1] = f2bf(src[t * 2 + 1]);
  if (t == 0) bb[o] = bsrc[oo];
}

// ---------------------------------------------------------------------------
// Prep 2: streaming cast x (n,512,4096) f32 -> xb bf16 (same layout).
// ---------------------------------------------------------------------------
__global__ __launch_bounds__(256) void k_prep_xb(const float* __restrict__ x,
                                                 ushort* __restrict__ xb)
{
  size_t i = ((size_t)blockIdx.x * 256 + threadIdx.x) * 8;
  f32x4 a = *(const f32x4*)(x + i);
  f32x4 b = *(const f32x4*)(x + i + 4);
  s16x8 w;
  #pragma unroll
  for (int j = 0; j < 4; ++j) {
    w[j]     = (short)f2bf(a[j]);
    w[j + 4] = (short)f2bf(b[j]);
  }
  *(s16x8*)(xb + i) = w;
}

// ---------------------------------------------------------------------------
// Kernel 1: [K;Q] = Wb @ x + bias, bf16 MFMA, 256x256 tile, BK=64, 8 waves.
// 1D grid (512) with XCD swizzle; oy fastest so the 2 oy-siblings sharing
// an xb B-panel land on the same XCD (L2 reuse).
// ---------------------------------------------------------------------------
#define QBM 256
#define QBN 256
#define QBK 64

#define TRRD(dst, off_lit)                                                       \
  asm volatile("ds_read_b64_tr_b16 %0, %1 offset:" #off_lit                      \
               : "=v"(dst) : "v"(trp));

__global__ __launch_bounds__(512) void k_kq_mfma(
    const ushort* __restrict__ Wb,   // [512][512] bf16
    const ushort* __restrict__ xb,   // [n][512][4096] bf16
    const float* __restrict__ bb,    // [512]
    ushort* __restrict__ Kbuf,       // [n][256][4096] bf16
    ushort* __restrict__ qT)         // [n][4096][256] bf16 (normalized Q^T)
{
  extern __shared__ __align__(16) char smem[];
  const int wgid = xcd_swz(blockIdx.x, 64);   // 512 blocks
  const int oy = wgid & 1;
  const int lx = (wgid >> 1) & 15;
  const int n  = wgid >> 5;
  const int tid  = threadIdx.x;
  const int wave = tid >> 6, lane = tid & 63;
  const int wr = wave >> 2, wc = wave & 3;   // 2 x 4

  f32x4 acc[8][4] = {};

  const ushort* gA = Wb + (size_t)(oy * QBM) * C_IN;
  const ushort* gX = xb + (size_t)n * C_IN * L + (size_t)lx * QBN;  // + c*L + l

  #define ASTG(buf, k0)                                                          \
    {                                                                            \
      ushort* As_ = (ushort*)(smem + (buf) * 65536);                             \
      _Pragma("unroll")                                                          \
      for (int i_ = 0; i_ < 4; ++i_) {                                           \
        int rbase_ = wave * 32 + i_ * 8;                                         \
        int row_ = rbase_ + (lane >> 3);                                         \
        int ss_ = (lane & 7) ^ (row_ & 7);                                       \
        __builtin_amdgcn_global_load_lds(                                        \
            (const __attribute__((address_space(1))) uint32_t*)(gA + (size_t)row_ * C_IN + (k0) + ss_ * 8), \
            (__attribute__((address_space(3))) uint32_t*)(As_ + rbase_ * QBK),   \
            16, 0, 0);                                                           \
      }                                                                          \
    }

  #define BSTG(buf, k0)                                                          \
    {                                                                            \
      ushort* Bs_ = (ushort*)(smem + (buf) * 65536 + 32768);                     \
      _Pragma("unroll")                                                          \
      for (int i_ = 0; i_ < 4; ++i_) {                                           \
        int chunk_ = i_ * 512 + tid;                                             \
        int lh_ = chunk_ & 1, crow_ = (chunk_ >> 1) & 3;                         \
        int c4_ = (chunk_ >> 3) & 15, l16_ = chunk_ >> 7;                        \
        __builtin_amdgcn_global_load_lds(                                        \
            (const __attribute__((address_space(1))) uint32_t*)(gX + (size_t)((k0) + c4_ * 4 + crow_) * L + l16_ * 16 + lh_ * 8), \
            (__attribute__((address_space(3))) uint32_t*)(Bs_ + (i_ * 512 + wave * 64) * 8), \
            16, 0, 0);                                                           \
      }                                                                          \
    }

  ASTG(0, 0)
  BSTG(0, 0)
  __syncthreads();

  const int nt = C_IN / QBK;   // 8
  for (int t = 0; t < nt; ++t) {
    if (t < nt - 1) {
      ASTG((t + 1) & 1, (t + 1) * QBK)
      BSTG((t + 1) & 1, (t + 1) * QBK)
    }
    ushort* As = (ushort*)(smem + (t & 1) * 65536);
    ushort* Bs = (ushort*)(smem + (t & 1) * 65536 + 32768);
    __builtin_amdgcn_s_setprio(1);
    #pragma unroll
    for (int ks = 0; ks < 2; ++ks) {
      s16x8 af[8];
      #pragma unroll
      for (int m = 0; m < 8; ++m) {
        int row = wr * 128 + m * 16 + (lane & 15);
        int slot = (ks * 4 + (lane >> 4)) ^ (row & 7);
        af[m] = *(const s16x8*)&As[row * QBK + slot * 8];
      }
      const int trb = wc * 8192 + ks * 1024 + (lane >> 4) * 256 + (lane & 15) * 2;
      __attribute__((address_space(3))) char* trp =
          (__attribute__((address_space(3))) char*)Bs + trb;
      u32x2 lo0, hi0, lo1, hi1, lo2, hi2, lo3, hi3;
      TRRD(lo0, 0)    TRRD(hi0, 128)
      TRRD(lo1, 2048) TRRD(hi1, 2176)
      TRRD(lo2, 4096) TRRD(hi2, 4224)
      TRRD(lo3, 6144) TRRD(hi3, 6272)
      asm volatile("s_waitcnt lgkmcnt(0)" ::: "memory");
      __builtin_amdgcn_sched_barrier(0);
      s16x8 bfr[4];
      bfr[0] = mk8(lo0, hi0);
      bfr[1] = mk8(lo1, hi1);
      bfr[2] = mk8(lo2, hi2);
      bfr[3] = mk8(lo3, hi3);
      #pragma unroll
      for (int m = 0; m < 8; ++m)
        #pragma unroll
        for (int nn = 0; nn < 4; ++nn)
          acc[m][nn] = __builtin_amdgcn_mfma_f32_16x16x32_bf16(af[m], bfr[nn], acc[m][nn], 0, 0, 0);
    }
    __builtin_amdgcn_s_setprio(0);
    __syncthreads();
  }
  #undef ASTG
  #undef BSTG

  if (oy == 0) {
    float* ep = (float*)smem + wave * (16 * 68);
    const int erow = lane >> 4;
    const int ecol = lane & 15;
    const float* bias = bb + wr * 128;
    ushort* outp = Kbuf + ((size_t)n * 256 + wr * 128) * L
                 + (size_t)lx * QBN + wc * 64;
    #pragma unroll
    for (int m = 0; m < 8; ++m) {
      #pragma unroll
      for (int nn = 0; nn < 4; ++nn)
        #pragma unroll
        for (int r = 0; r < 4; ++r)
          ep[(erow * 4 + r) * 68 + nn * 16 + ecol] = acc[m][nn][r];
      #pragma unroll
      for (int p = 0; p < 4; ++p) {
        int row = p * 4 + erow;
        f32x4 v = *(const f32x4*)&ep[row * 68 + ecol * 4];
        float bo = bias[m * 16 + row];
        uint2 pk;
        pk.x = (uint32_t)f2bf(v[0] + bo) | ((uint32_t)f2bf(v[1] + bo) << 16);
        pk.y = (uint32_t)f2bf(v[2] + bo) | ((uint32_t)f2bf(v[3] + bo) << 16);
        *(uint2*)&outp[(size_t)(m * 16 + row) * L + ecol * 4] = pk;
      }
    }
  } else {
    const float* bias = bb + 256 + wr * 128;
    ushort* qbase = qT + (size_t)n * L * KC;
    const int g4 = (lane >> 4) * 4;
    #pragma unroll
    for (int hp = 0; hp < 4; ++hp) {
      const int m0 = 2 * hp, m1 = 2 * hp + 1;
      const float b0_0 = bias[m0 * 16 + g4 + 0], b0_1 = bias[m0 * 16 + g4 + 1];
      const float b0_2 = bias[m0 * 16 + g4 + 2], b0_3 = bias[m0 * 16 + g4 + 3];
      const float b1_0 = bias[m1 * 16 + g4 + 0], b1_1 = bias[m1 * 16 + g4 + 1];
      const float b1_2 = bias[m1 * 16 + g4 + 2], b1_3 = bias[m1 * 16 + g4 + 3];
      #pragma unroll
      for (int nn = 0; nn < 4; ++nn) {
        float v0[4], v1[4];
        v0[0] = acc[m0][nn][0] + b0_0; v0[1] = acc[m0][nn][1] + b0_1;
        v0[2] = acc[m0][nn][2] + b0_2; v0[3] = acc[m0][nn][3] + b0_3;
        v1[0] = acc[m1][nn][0] + b1_0; v1[1] = acc[m1][nn][1] + b1_1;
        v1[2] = acc[m1][nn][2] + b1_2; v1[3] = acc[m1][nn][3] + b1_3;
        float mx = fmaxf(fmaxf(fmaxf(v0[0], v0[1]), fmaxf(v0[2], v0[3])),
                         fmaxf(fmaxf(v1[0], v1[1]), fmaxf(v1[2], v1[3])));
        mx = fmaxf(mx, __shfl_xor(mx, 16));
        mx = fmaxf(mx, __shfl_xor(mx, 32));
        float e0[4], e1[4];
        float s = 0.f;
        #pragma unroll
        for (int r = 0; r < 4; ++r) { e0[r] = __expf(v0[r] - mx); s += e0[r]; }
        #pragma unroll
        for (int r = 0; r < 4; ++r) { e1[r] = __expf(v1[r] - mx); s += e1[r]; }
        s += __shfl_xor(s, 16);
        s += __shfl_xor(s, 32);
        float inv = 1.0f / s;
        int l = lx * QBN + wc * 64 + nn * 16 + (lane & 15);
        ushort* dst = qbase + (size_t)l * KC + wr * 128;
        uint2 p0, p1;
        p0.x = (uint32_t)f2bf(e0[0] * inv) | ((uint32_t)f2bf(e0[1] * inv) << 16);
        p0.y = (uint32_t)f2bf(e0[2] * inv) | ((uint32_t)f2bf(e0[3] * inv) << 16);
        p1.x = (uint32_t)f2bf(e1[0] * inv) | ((uint32_t)f2bf(e1[1] * inv) << 16);
        p1.y = (uint32_t)f2bf(e1[2] * inv) | ((uint32_t)f2bf(e1[3] * inv) << 16);
        *(uint2*)&dst[m0 * 16 + g4] = p0;
        *(uint2*)&dst[m1 * 16 + g4] = p1;
      }
    }
  }
}

// ---------------------------------------------------------------------------
// Reductions
// ---------------------------------------------------------------------------
__device__ inline float blockReduceMax(float v, float* red) {
  #pragma unroll
  for (int off = 32; off > 0; off >>= 1)
    v = fmaxf(v, __shfl_down(v, off, 64));
  int tid = threadIdx.x;
  if ((tid & 63) == 0) red[tid >> 6] = v;
  __syncthreads();
  return fmaxf(fmaxf(red[0], red[1]), fmaxf(red[2], red[3]));
}
__device__ inline float blockReduceSum(float v, float* red) {
  #pragma unroll
  for (int off = 32; off > 0; off >>= 1)
    v += __shfl_down(v, off, 64);
  int tid = threadIdx.x;
  if ((tid & 63) == 0) red[tid >> 6] = v;
  __syncthreads();
  return red[0] + red[1] + red[2] + red[3];
}

// ---------------------------------------------------------------------------
// Kernel 2: K softmax stats over L per (n,row) -> kmax, kinv (stats only)
// ---------------------------------------------------------------------------
__global__ __launch_bounds__(256) void k_kstats3(const ushort* __restrict__ Kbuf,
                                                 float* __restrict__ kmax,
                                                 float* __restrict__ kinv)
{
  const int r = blockIdx.x;
  const int n = blockIdx.y;
  const ushort* row = Kbuf + ((size_t)n * 256 + r) * L;
  __shared__ float red1[4];
  __shared__ float red2[4];
  const int tid = threadIdx.x;
  s16x8 a = *(const s16x8*)(row + tid * 16);
  s16x8 b = *(const s16x8*)(row + tid * 16 + 8);
  float v[16];
  #pragma unroll
  for (int j = 0; j < 8; ++j) { v[j] = bf2f((ushort)a[j]); v[8 + j] = bf2f((ushort)b[j]); }
  float m = -3.0e38f;
  #pragma unroll
  for (int j = 0; j < 16; ++j) m = fmaxf(m, v[j]);
  m = blockReduceMax(m, red1);
  float s = 0.f;
  #pragma unroll
  for (int j = 0; j < 16; ++j) s += __expf(v[j] - m);
  s = blockReduceSum(s, red2);
  if (tid == 0) { kmax[n * KC + r] = m; kinv[n * KC + r] = 1.0f / s; }
}

// ---------------------------------------------------------------------------
// Kernel 3: G[c][k] = sum_l x[c,l] * softmax(K)[k,l]  (per n, l-chunk part).
// 1D grid (256) with XCD swizzle; cm fastest so the 4 cm-siblings sharing
// a Kbuf panel land on the same XCD.
// ---------------------------------------------------------------------------
#define GBK 64

__global__ __launch_bounds__(512) void k_G(
    const ushort* __restrict__ xb,   // [n][512][4096] bf16
    const ushort* __restrict__ Kbuf, // [n][256][4096] bf16
    const float* __restrict__ kmax,
    const float* __restrict__ kinv,
    float* __restrict__ Gp)          // [n][4][512][256] f32
{
  extern __shared__ __align__(16) char smem[];
  const int wgid = xcd_swz(blockIdx.x, 32);   // 256 blocks
  const int cm = wgid & 3;
  const int lc = (wgid >> 2) & 3;
  const int n  = wgid >> 4;
  const int tid  = threadIdx.x;
  const int wave = tid >> 6, lane = tid & 63;
  const int wr = wave >> 2, wc = wave & 3;   // 2 x 4

  f32x4 acc[4][4] = {};

  const ushort* gxb = xb   + ((size_t)n * C_IN + cm * 128) * L + lc * 1024;
  const ushort* gK  = Kbuf + (size_t)n * 256 * L + lc * 1024;

  const int brow = tid >> 1;
  const int bseg0 = (tid & 1) * 4;
  const float mk = kmax[n * KC + brow];
  const float ik = kinv[n * KC + brow];

  #define ASTAGE(buf, k0)                                                        \
    {                                                                            \
      ushort* As_ = (ushort*)(smem + (buf) * 49152);                             \
      _Pragma("unroll")                                                          \
      for (int i_ = 0; i_ < 2; ++i_) {                                           \
        int rbase_ = wave * 16 + i_ * 8;                                         \
        int row_ = rbase_ + (lane >> 3);                                         \
        int ss_ = (lane & 7) ^ (row_ & 7);                                       \
        __builtin_amdgcn_global_load_lds(                                        \
            (const __attribute__((address_space(1))) uint32_t*)(gxb + (size_t)row_ * L + (k0) + ss_ * 8), \
            (__attribute__((address_space(3))) uint32_t*)(As_ + rbase_ * GBK),   \
            16, 0, 0);                                                           \
      }                                                                          \
    }

  #define BLOAD(k0)                                                              \
    _Pragma("unroll")                                                            \
    for (int i_ = 0; i_ < 4; ++i_)                                               \
      bk[i_] = *(const s16x8*)(gK + (size_t)brow * L + (k0) + (bseg0 + i_) * 8);

  #define BWRITE(buf)                                                            \
    {                                                                            \
      ushort* Bs_ = (ushort*)(smem + (buf) * 49152 + 16384);                     \
      _Pragma("unroll")                                                          \
      for (int i_ = 0; i_ < 4; ++i_) {                                           \
        s16x8 w_;                                                                \
        _Pragma("unroll")                                                        \
        for (int j_ = 0; j_ < 8; ++j_)                                           \
          w_[j_] = (short)f2bf(__expf(bf2f((ushort)bk[i_][j_]) - mk) * ik);      \
        *(s16x8*)&Bs_[brow * GBK + ((bseg0 + i_) ^ (brow & 7)) * 8] = w_;        \
      }                                                                          \
    }

  s16x8 bk[4];

  BLOAD(0)
  ASTAGE(0, 0)
  BWRITE(0)
  __syncthreads();

  const int nt = 1024 / GBK;   // 16
  for (int t = 0; t < nt; ++t) {
    const int cb = t & 1, nb = cb ^ 1;
    if (t < nt - 1) {
      BLOAD((t + 1) * GBK)
      ASTAGE(nb, (t + 1) * GBK)
    }
    ushort* As = (ushort*)(smem + cb * 49152);
    ushort* Bs = (ushort*)(smem + cb * 49152 + 16384);
    __builtin_amdgcn_s_setprio(1);
    #pragma unroll
    for (int ks = 0; ks < 2; ++ks) {
      s16x8 af[4], bfr[4];
      #pragma unroll
      for (int m = 0; m < 4; ++m) {
        int row = wr * 64 + m * 16 + (lane & 15);
        int slot = (ks * 4 + (lane >> 4)) ^ (row & 7);
        af[m] = *(const s16x8*)&As[row * GBK + slot * 8];
      }
      #pragma unroll
      for (int nn = 0; nn < 4; ++nn) {
        int row = wc * 64 + nn * 16 + (lane & 15);
        int slot = (ks * 4 + (lane >> 4)) ^ (row & 7);
        bfr[nn] = *(const s16x8*)&Bs[row * GBK + slot * 8];
      }
      #pragma unroll
      for (int m = 0; m < 4; ++m)
        #pragma unroll
        for (int nn = 0; nn < 4; ++nn)
          acc[m][nn] = __builtin_amdgcn_mfma_f32_16x16x32_bf16(af[m], bfr[nn], acc[m][nn], 0, 0, 0);
    }
    __builtin_amdgcn_s_setprio(0);
    if (t < nt - 1) BWRITE(nb)
    __syncthreads();
  }
  #undef ASTAGE
  #undef BLOAD
  #undef BWRITE

  float* ep = (float*)smem + wave * (16 * 68);
  const int erow = lane >> 4;
  const int ecol = lane & 15;
  float* op = Gp + (((size_t)n * 4 + lc) * 512 + cm * 128 + wr * 64) * 256 + wc * 64;
  #pragma unroll
  for (int m = 0; m < 4; ++m) {
    #pragma unroll
    for (int nn = 0; nn < 4; ++nn)
      #pragma unroll
      for (int r = 0; r < 4; ++r)
        ep[(erow * 4 + r) * 68 + nn * 16 + ecol] = acc[m][nn][r];
    #pragma unroll
    for (int p = 0; p < 4; ++p) {
      int row16 = p * 4 + erow;
      f32x4 v = *(const f32x4*)&ep[row16 * 68 + ecol * 4];
      *(f32x4*)&op[(size_t)(m * 16 + row16) * 256 + ecol * 4] = v;
    }
  }
}

// ---------------------------------------------------------------------------
// Kernel 4a: F[h][o][c] = sum_v We[o][h*64+v] * Wv[h*64+v][c]  (bf16)
//            Fb[h][o]   = sum_v We[o][h*64+v] * bv[h*64+v]     (f32)
// ---------------------------------------------------------------------------
__global__ __launch_bounds__(256) void k_F(
    const float* __restrict__ Wv, const float* __restrict__ bv,
    const float* __restrict__ We,
    ushort* __restrict__ F, float* __restrict__ Fb)
{
  const int h  = blockIdx.x;   // 8
  const int og = blockIdx.y;   // 32
  const int tid = threadIdx.x;
  __shared__ float Ws[16][64];
  #pragma unroll
  for (int i = 0; i < 4; ++i) {
    int e = tid + i * 256;
    int o = e >> 6, v = e & 63;
    Ws[o][v] = We[(size_t)(og * 16 + o) * VC + h * 64 + v];
  }
  __syncthreads();
  const int c2 = tid * 2;
  float acc[16][2] = {};
  for (int v = 0; v < 64; ++v) {
    float2 w = *(const float2*)&Wv[(size_t)(h * 64 + v) * C_IN + c2];
    #pragma unroll
    for (int o = 0; o < 16; ++o) {
      acc[o][0] += Ws[o][v] * w.x;
      acc[o][1] += Ws[o][v] * w.y;
    }
  }
  ushort* Fh = F + ((size_t)h * 512 + og * 16) * C_IN;
  #pragma unroll
  for (int o = 0; o < 16; ++o) {
    uint32_t pk = (uint32_t)f2bf(acc[o][0]) | ((uint32_t)f2bf(acc[o][1]) << 16);
    *(uint32_t*)&Fh[(size_t)o * C_IN + c2] = pk;
  }
  if (tid < 16) {
    float s = 0.f;
    for (int v = 0; v < 64; ++v) s += Ws[tid][v] * bv[h * 64 + v];
    Fb[h * 512 + og * 16 + tid] = s;
  }
}

// ---------------------------------------------------------------------------
// Kernel 4b: M[o][h*32+k] = sum_c F_h[o][c] * G[c][h*32+k] + Fb[h][o]  (bf16)
// 1D grid (512) with XCD swizzle; oy fastest so the 4 oy-siblings sharing
// a Gp slice land on the same XCD.
// ---------------------------------------------------------------------------
__global__ __launch_bounds__(256) void k_M(
    const float* __restrict__ Gp,   // [n][4][512][256] f32
    const ushort* __restrict__ F,   // [8][512][512] bf16
    const float* __restrict__ Fb,   // [8][512] f32
    ushort* __restrict__ Mbuf)      // [n][512][256] bf16
{
  const int wgid = xcd_swz(blockIdx.x, 64);   // 512 blocks
  const int oy = wgid & 3;
  const int h  = (wgid >> 2) & 7;
  const int n  = wgid >> 5;
  const int tid = threadIdx.x, wave = tid >> 6, lane = tid & 63;

  __shared__ __align__(16) char smem[32768 + 32768 + 9216];
  ushort* GTs = (ushort*)smem;                  // [32][512] swizzled, 32 KB

  #pragma unroll
  for (int i = 0; i < 16; ++i) {
    int e = tid + i * 256;              // 4096 = 512 c x 8 kq
    int c = e >> 3, kq = e & 7;
    int k = kq * 4;
    const float* gp = Gp + ((size_t)n * 4 * 512 + c) * 256 + h * HK + k;
    f32x4 s = *(const f32x4*)gp;
    s += *(const f32x4*)(gp + (size_t)512 * 256);
    s += *(const f32x4*)(gp + (size_t)2 * 512 * 256);
    s += *(const f32x4*)(gp + (size_t)3 * 512 * 256);
    #pragma unroll
    for (int j = 0; j < 4; ++j) {
      int kk = k + j;
      GTs[kk * 512 + (((c >> 3) ^ (kk & 7)) * 8) + (c & 7)] = f2bf(s[j]);
    }
  }

  const ushort* gA = F + ((size_t)h * 512 + oy * 128) * C_IN;

  #define MSTAGE(buf, k0)                                                        \
    {                                                                            \
      ushort* As_ = (ushort*)(smem + 32768 + (buf) * 16384);                     \
      _Pragma("unroll")                                                          \
      for (int i_ = 0; i_ < 4; ++i_) {                                           \
        int rbase_ = wave * 32 + i_ * 8;                                         \
        int row_ = rbase_ + (lane >> 3);                                         \
        int ss_ = (lane & 7) ^ (row_ & 7);                                       \
        __builtin_amdgcn_global_load_lds(                                        \
            (const __attribute__((address_space(1))) uint32_t*)(gA + (size_t)row_ * C_IN + (k0) + ss_ * 8), \
            (__attribute__((address_space(3))) uint32_t*)(As_ + rbase_ * 64),    \
            16, 0, 0);                                                           \
      }                                                                          \
    }

  f32x4 acc[2][2] = {};

  MSTAGE(0, 0)
  __syncthreads();

  const int nt = C_IN / 64;   // 8
  for (int t = 0; t < nt; ++t) {
    if (t < nt - 1) MSTAGE((t + 1) & 1, (t + 1) * 64)
    ushort* As = (ushort*)(smem + 32768 + (t & 1) * 16384);
    __builtin_amdgcn_s_setprio(1);
    #pragma unroll
    for (int ks = 0; ks < 2; ++ks) {
      s16x8 af[2], bfr[2];
      #pragma unroll
      for (int m = 0; m < 2; ++m) {
        int row = wave * 32 + m * 16 + (lane & 15);
        int slot = (ks * 4 + (lane >> 4)) ^ (row & 7);
        af[m] = *(const s16x8*)&As[row * 64 + slot * 8];
      }
      #pragma unroll
      for (int nf = 0; nf < 2; ++nf) {
        int kr = nf * 16 + (lane & 15);
        int slot = (t * 8 + ks * 4 + (lane >> 4)) ^ (kr & 7);
        bfr[nf] = *(const s16x8*)&GTs[kr * 512 + slot * 8];
      }
      #pragma unroll
      for (int m = 0; m < 2; ++m)
        #pragma unroll
        for (int nf = 0; nf < 2; ++nf)
          acc[m][nf] = __builtin_amdgcn_mfma_f32_16x16x32_bf16(af[m], bfr[nf], acc[m][nf], 0, 0, 0);
    }
    __builtin_amdgcn_s_setprio(0);
    __syncthreads();
  }
  #undef MSTAGE

  float* ep = (float*)(smem + 65536) + wave * (16 * 36);
  const int erow = lane >> 4;
  const int ecol = lane & 15;
  #pragma unroll
  for (int m = 0; m < 2; ++m) {
    #pragma unroll
    for (int nf = 0; nf < 2; ++nf)
      #pragma unroll
      for (int r = 0; r < 4; ++r)
        ep[(erow * 4 + r) * 36 + nf * 16 + ecol] = acc[m][nf][r];
    #pragma unroll
    for (int p = 0; p < 2; ++p) {
      int row16 = p * 8 + (lane >> 3);
      int c4 = (lane & 7) * 4;
      f32x4 v = *(const f32x4*)&ep[row16 * 36 + c4];
      int o = oy * 128 + wave * 32 + m * 16 + row16;
      float fb = Fb[h * 512 + o];
      uint2 pk;
      pk.x = (uint32_t)f2bf(v[0] + fb) | ((uint32_t)f2bf(v[1] + fb) << 16);
      pk.y = (uint32_t)f2bf(v[2] + fb) | ((uint32_t)f2bf(v[3] + fb) << 16);
      *(uint2*)&Mbuf[((size_t)n * 512 + o) * KC + h * HK + c4] = pk;
    }
  }
}

// ---------------------------------------------------------------------------
// Kernel 5: out = x + be + M @ q_smT via MFMA.  Round-15 proven (epilogue
// issues all 16 residual x loads upfront, no barriers in epilogue).
// ---------------------------------------------------------------------------
#define BM 128
#define BN 128
#define BK 32

__global__ __launch_bounds__(256) void k_final_mfma(
    const ushort* __restrict__ Mb,   // [n][512][256] bf16
    const ushort* __restrict__ qT,   // [n][4096][256] bf16
    const float* __restrict__ x,
    const float* __restrict__ be,
    float* __restrict__ out)
{
  const int n  = blockIdx.z;
  const int oy = blockIdx.y;   // 4
  const int lx = blockIdx.x;   // 32
  const int tid  = threadIdx.x;
  const int wave = tid >> 6, lane = tid & 63;
  const int wr = wave >> 1, wc = wave & 1;

  __shared__ __align__(16) char smem[32768 + 17408];

  f32x4 acc[4][4] = {};

  const ushort* gA = Mb + ((size_t)n * 512 + oy * BM) * KC;
  const ushort* gB = qT + ((size_t)n * L + lx * BN) * KC;

  const int r0 = wave * 32;
  const int lrow = lane >> 2;

  #define FSTAGE(buf, k0)                                                        \
    {                                                                            \
      ushort* As_ = (ushort*)(smem + (buf) * 16384);                             \
      ushort* Bs_ = (ushort*)(smem + (buf) * 16384 + 8192);                      \
      _Pragma("unroll")                                                          \
      for (int i_ = 0; i_ < 2; ++i_) {                                           \
        int row_ = r0 + i_ * 16 + lrow;                                          \
        int ss_ = (lane & 3) ^ ((row_ >> 1) & 3);                                \
        __builtin_amdgcn_global_load_lds(                                        \
            (const __attribute__((address_space(1))) uint32_t*)(gA + (size_t)row_ * KC + (k0) + ss_ * 8), \
            (__attribute__((address_space(3))) uint32_t*)(As_ + (r0 + i_ * 16) * BK), \
            16, 0, 0);                                                           \
        __builtin_amdgcn_global_load_lds(                                        \
            (const __attribute__((address_space(1))) uint32_t*)(gB + (size_t)row_ * KC + (k0) + ss_ * 8), \
            (__attribute__((address_space(3))) uint32_t*)(Bs_ + (r0 + i_ * 16) * BK), \
            16, 0, 0);                                                           \
      }                                                                          \
    }

  FSTAGE(0, 0)
  __syncthreads();

  const int nt = KC / BK;   // 8
  for (int t = 0; t < nt; ++t) {
    if (t < nt - 1) FSTAGE((t + 1) & 1, (t + 1) * BK)
    ushort* As = (ushort*)(smem + (t & 1) * 16384);
    ushort* Bs = (ushort*)(smem + (t & 1) * 16384 + 8192);
    s16x8 af[4], bfr[4];
    #pragma unroll
    for (int m = 0; m < 4; ++m) {
      int row = wr * 64 + m * 16 + (lane & 15);
      int slot = (lane >> 4) ^ ((row >> 1) & 3);
      af[m] = *(const s16x8*)&As[row * BK + slot * 8];
    }
    #pragma unroll
    for (int nn = 0; nn < 4; ++nn) {
      int row = wc * 64 + nn * 16 + (lane & 15);
      int slot = (lane >> 4) ^ ((row >> 1) & 3);
      bfr[nn] = *(const s16x8*)&Bs[row * BK + slot * 8];
    }
    __builtin_amdgcn_s_setprio(1);
    #pragma unroll
    for (int m = 0; m < 4; ++m)
      #pragma unroll
      for (int nn = 0; nn < 4; ++nn)
        acc[m][nn] = __builtin_amdgcn_mfma_f32_16x16x32_bf16(af[m], bfr[nn], acc[m][nn], 0, 0, 0);
    __builtin_amdgcn_s_setprio(0);
    __syncthreads();
  }
  #undef FSTAGE

  // Epilogue: issue all residual x loads first (16-deep MLP), then overlap
  // the wave-private LDS transpose with them.  No barriers -> no drain.
  const int erow = lane >> 4;
  const int ecol = lane & 15;
  const float* xp = x + ((size_t)n * 512 + oy * BM + wr * 64) * L
                  + (size_t)lx * BN + wc * 64;
  f32x4 xpre[4][4];
  #pragma unroll
  for (int m = 0; m < 4; ++m)
    #pragma unroll
    for (int p = 0; p < 4; ++p)
      xpre[m][p] = *(const f32x4*)&xp[(size_t)(m * 16 + p * 4 + erow) * L + ecol * 4];

  float* ep = (float*)(smem + 32768) + wave * (16 * 68);
  const float* bias = be + oy * BM + wr * 64;
  float* op = out + ((size_t)n * 512 + oy * BM + wr * 64) * L
            + (size_t)lx * BN + wc * 64;
  #pragma unroll
  for (int m = 0; m < 4; ++m) {
    #pragma unroll
    for (int nn = 0; nn < 4; ++nn)
      #pragma unroll
      for (int r = 0; r < 4; ++r)
        ep[(erow * 4 + r) * 68 + nn * 16 + ecol] = acc[m][nn][r];
    #pragma unroll
    for (int p = 0; p < 4; ++p) {
      int row = p * 4 + erow;
      f32x4 v = *(const f32x4*)&ep[row * 68 + ecol * 4];
      float bo = bias[m * 16 + row];
      v = v + xpre[m][p] + bo;
      *(f32x4*)&op[(size_t)(m * 16 + row) * L + ecol * 4] = v;
    }
  }
}

// ---------------------------------------------------------------------------
extern "C" void kernel_launch(void* const* d_in, const int* in_sizes, int n_in,
                              void* d_out, int out_size, void* d_ws, size_t ws_size,
                              hipStream_t stream)
{
  const float* x  = (const float*)d_in[0];
  const float* Wk = (const float*)d_in[1];
  const float* bk = (const float*)d_in[2];
  const float* Wq = (const float*)d_in[3];
  const float* bq = (const float*)d_in[4];
  const float* Wv = (const float*)d_in[5];
  const float* bv = (const float*)d_in[6];
  const float* We = (const float*)d_in[7];
  const float* be = (const float*)d_in[8];
  float* out = (float*)d_out;

  char* ws = (char*)d_ws;
  size_t off = 0;
  ushort* Kbuf = (ushort*)(ws + off); off += (size_t)N_BATCH * 256 * L * 2;        // 33.6 MB
  ushort* xb   = (ushort*)(ws + off); off += (size_t)N_BATCH * C_IN * L * 2;       // 67.1 MB
  ushort* Wb   = (ushort*)(ws + off); off += (size_t)512 * C_IN * 2;               // 0.5 MB
  float*  bb   = (float*)(ws + off);  off += (size_t)512 * 4;
  float*  kmax = (float*)(ws + off);  off += (size_t)N_BATCH * KC * 4;
  float*  kinv = (float*)(ws + off);  off += (size_t)N_BATCH * KC * 4;
  ushort* qT   = (ushort*)(ws + off); off += (size_t)N_BATCH * L * KC * 2;         // 33.6 MB
  float*  Gp   = (float*)(ws + off);  off += (size_t)N_BATCH * 4 * 512 * 256 * 4;  // 33.6 MB
  ushort* Fbuf = (ushort*)(ws + off); off += (size_t)NH * 512 * C_IN * 2;          // 4.2 MB
  float*  Fb   = (float*)(ws + off);  off += (size_t)NH * 512 * 4;
  ushort* Mbuf = (ushort*)(ws + off); off += (size_t)N_BATCH * 512 * KC * 2;       // 4.2 MB

  (void)hipFuncSetAttribute((const void*)k_kq_mfma,
                            hipFuncAttributeMaxDynamicSharedMemorySize, 131072);
  (void)hipFuncSetAttribute((const void*)k_G,
                            hipFuncAttributeMaxDynamicSharedMemorySize, 98304);

  k_prep_w<<<dim3(512), 256, 0, stream>>>(Wk, bk, Wq, bq, Wb, bb);
  k_F<<<dim3(NH, 32), 256, 0, stream>>>(Wv, bv, We, Fbuf, Fb);
  k_prep_xb<<<dim3(16384), 256, 0, stream>>>(x, xb);
  k_kq_mfma<<<dim3(512), 512, 131072, stream>>>(Wb, xb, bb, Kbuf, qT);
  k_kstats3<<<dim3(KC, N_BATCH), 256, 0, stream>>>(Kbuf, kmax, kinv);
  k_G<<<dim3(256), 512, 98304, stream>>>(xb, Kbuf, kmax, kinv, Gp);
  k_M<<<dim3(512), 256, 0, stream>>>(Gp, Fbuf, Fb, Mbuf);
  k_final_mfma<<<dim3(32, 4, N_BATCH), 256, 0, stream>>>(Mbuf, qT, x, be, out);
}